// Round 12
// baseline (1025.718 us; speedup 1.0000x reference)
//
#include <hip/hip_runtime.h>

#define N_NODES 50000
#define N_EDGES 800000
#define DIM 256
#define ACT 64
#define SCAN_B 256
#define SCAN_NB ((N_NODES + SCAN_B - 1) / SCAN_B)   // 196
#define SLICE_ELEMS ((size_t)N_NODES * 32)          // elems per 32-dim slice
#define AGG_CHUNKS 512
#define TOTAL_GROUPS (AGG_CHUNKS * 32)              // 16384 groups per slice
#define CSR_MAX (N_EDGES + 8 * N_NODES + 64)        // padded-to-8 CSR + overread slack
#define NBINS 16

typedef __attribute__((ext_vector_type(8))) short short8_t;
typedef __attribute__((ext_vector_type(4))) float f32x4;
typedef __attribute__((ext_vector_type(4))) unsigned short ushort4_t;

__device__ __forceinline__ unsigned short f2b(float x) {   // f32 -> bf16 RNE
    unsigned u = __float_as_uint(x);
    unsigned r = u + 0x7FFFu + ((u >> 16) & 1u);
    return (unsigned short)(r >> 16);
}

// ---------------- weight transpose + convert ----------------

__global__ __launch_bounds__(256) void k_cvt_wt2(const float* __restrict__ W1,
                                                 const float* __restrict__ W2,
                                                 unsigned short* __restrict__ W1t,
                                                 unsigned short* __restrict__ W2t) {
    int b = blockIdx.x;
    const float* W = (b < 256) ? W1 : W2;
    unsigned short* Wt = (b < 256) ? W1t : W2t;
    int i = (b & 255) * 256 + threadIdx.x;
    int k = i >> 8, n = i & 255;
    Wt[n * DIM + k] = f2b(W[k * DIM + n]);
}

// ---------------- degree (degi pre-zeroed; self-loop accounted as +1 in scan) ----------------

__global__ void k_deg_count(const int* __restrict__ ei, int* degi) {
    int e = blockIdx.x * blockDim.x + threadIdx.x;
    if (e < N_EDGES) atomicAdd(&degi[ei[N_EDGES + e]], 1);  // dst row
}

// ---------------- degree histogram (by padded round count) ----------------

__global__ __launch_bounds__(256) void k_hist(const int* __restrict__ degi, int* hist) {
    int i = blockIdx.x * blockDim.x + threadIdx.x;
    if (i >= N_NODES) return;
    int rounds = ((degi[i] + 8) & ~7) >> 3;   // padded slots / 8
    if (rounds > NBINS - 1) rounds = NBINS - 1;
    atomicAdd(&hist[rounds], 1);
}

// scatter nodes into degree-sorted order
__global__ __launch_bounds__(256) void k_perm(const int* __restrict__ degi,
                                              int* histbase, int* perm) {
    int i = blockIdx.x * blockDim.x + threadIdx.x;
    if (i >= N_NODES) return;
    int rounds = ((degi[i] + 8) & ~7) >> 3;
    if (rounds > NBINS - 1) rounds = NBINS - 1;
    int pos = atomicAdd(&histbase[rounds], 1);
    perm[pos] = i;
}

// ---------------- hierarchical exclusive scan over PADDED row lengths ----------------
// padded_len(i) = roundup8(degi[i] + 1); padding slots stay 0 = (src=0, norm=+0.0bf16).

__global__ __launch_bounds__(SCAN_B) void k_scan_local(const int* __restrict__ degi,
                                                       int* lexc, int* btot) {
    __shared__ int sm[SCAN_B];
    int t = threadIdx.x;
    int i = blockIdx.x * SCAN_B + t;
    int v = (i < N_NODES) ? ((degi[i] + 8) & ~7) : 0;   // roundup8(deg+1)
    sm[t] = v;
    __syncthreads();
#pragma unroll
    for (int off = 1; off < SCAN_B; off <<= 1) {
        int u = (t >= off) ? sm[t - off] : 0;
        __syncthreads();
        sm[t] += u;
        __syncthreads();
    }
    if (i < N_NODES) lexc[i] = sm[t] - v;
    if (t == SCAN_B - 1) btot[blockIdx.x] = sm[t];
}

// also scans the degree histogram (16 bins, thread 0 serial)
__global__ __launch_bounds__(SCAN_B) void k_scan_tops(const int* __restrict__ btot,
                                                      int* bbase, int* rowstart,
                                                      const int* __restrict__ hist,
                                                      int* histbase) {
    __shared__ int sm[SCAN_B];
    int t = threadIdx.x;
    int v = (t < SCAN_NB) ? btot[t] : 0;
    sm[t] = v;
    __syncthreads();
#pragma unroll
    for (int off = 1; off < SCAN_B; off <<= 1) {
        int u = (t >= off) ? sm[t - off] : 0;
        __syncthreads();
        sm[t] += u;
        __syncthreads();
    }
    if (t < SCAN_NB) bbase[t] = sm[t] - v;
    if (t == SCAN_NB - 1) rowstart[N_NODES] = sm[t];
    if (t == 0) {
        int acc = 0;
#pragma unroll
        for (int b = 0; b < NBINS; ++b) { int h = hist[b]; histbase[b] = acc; acc += h; }
    }
}

// csr4 entry: (src << 16) | bf16(norm)   -- src < 65536, norm in (0,1]
__global__ __launch_bounds__(SCAN_B) void k_scan_apply(const int* __restrict__ degi,
                                                       const int* __restrict__ lexc,
                                                       const int* __restrict__ bbase,
                                                       int* rowstart, int* fillpos,
                                                       float* dinv, unsigned* csr4) {
    int i = blockIdx.x * SCAN_B + threadIdx.x;
    if (i >= N_NODES) return;
    int rs = bbase[blockIdx.x] + lexc[i];
    rowstart[i] = rs;
    int d = degi[i] + 1;
    float di = rsqrtf((float)d);
    dinv[i] = di;
    csr4[rs] = ((unsigned)i << 16) | f2b(di * di);   // self-loop first in row
    fillpos[i] = rs + 1;
}

__global__ void k_fill_edge(const int* __restrict__ ei,
                            const float* __restrict__ dinv, int* fillpos,
                            unsigned* csr4) {
    int e = blockIdx.x * blockDim.x + threadIdx.x;
    if (e < N_EDGES) {
        int s = ei[e];
        int d = ei[N_EDGES + e];
        int p = atomicAdd(&fillpos[d], 1);
        csr4[p] = ((unsigned)s << 16) | f2b(dinv[s] * dinv[d]);
    }
}

// ---------------- bf16 MFMA GEMM: H = A @ Wt^T  (H SLICED; A fp32 row-major or sliced bf16) --

template <int AFP32>
__global__ __launch_bounds__(512) void k_gemm_mfma(const void* __restrict__ Ap,
                                                   const unsigned short* __restrict__ Wt,
                                                   unsigned short* __restrict__ H,
                                                   int M) {
    __shared__ char lds[49152];          // As 128x64 bf16 (16KB) + Bs 256x64 bf16 (32KB)
    char* AsB = lds;
    char* BsB = lds + 16384;

    int tid = threadIdx.x;
    int w = tid >> 6;
    int l = tid & 63;
    int wr = w >> 2, wc = w & 3;
    int r0 = blockIdx.x * 128;

    f32x4 acc[4][4];
#pragma unroll
    for (int i = 0; i < 4; ++i)
#pragma unroll
        for (int j = 0; j < 4; ++j) acc[i][j] = (f32x4)(0.f);

    for (int kt = 0; kt < 4; ++kt) {
        int k0 = kt * 64;
#pragma unroll
        for (int i = 0; i < 2; ++i) {
            int c = tid + i * 512;
            int row = c >> 3, kc = c & 7;
            int gg = r0 + row; if (gg >= M) gg = M - 1;
            short8_t v;
            if (AFP32) {
                const float* A = (const float*)Ap;
                const float4* src = (const float4*)(A + (size_t)gg * DIM + k0 + kc * 8);
                float4 f0 = src[0], f1 = src[1];
                v[0] = (short)f2b(f0.x); v[1] = (short)f2b(f0.y);
                v[2] = (short)f2b(f0.z); v[3] = (short)f2b(f0.w);
                v[4] = (short)f2b(f1.x); v[5] = (short)f2b(f1.y);
                v[6] = (short)f2b(f1.z); v[7] = (short)f2b(f1.w);
            } else {
                const unsigned short* A = (const unsigned short*)Ap;
                int k = k0 + kc * 8;
                int slice = k >> 5, within = k & 31;
                v = *(const short8_t*)(A + (size_t)slice * SLICE_ELEMS + (size_t)gg * 32 + within);
            }
            int off = (row * 128 + kc * 16) ^ ((row & 7) << 4);
            *(short8_t*)(AsB + off) = v;
        }
#pragma unroll
        for (int i = 0; i < 4; ++i) {
            int c = tid + i * 512;
            int n = c >> 3, kc = c & 7;
            short8_t v = *(const short8_t*)(Wt + n * DIM + k0 + kc * 8);
            int off = (n * 128 + kc * 16) ^ ((n & 7) << 4);
            *(short8_t*)(BsB + off) = v;
        }
        __syncthreads();

#pragma unroll
        for (int kf = 0; kf < 2; ++kf) {
            int kb = kf * 64 + (l >> 4) * 16;
            short8_t a[4], b[4];
#pragma unroll
            for (int fm = 0; fm < 4; ++fm) {
                int ra = wr * 64 + fm * 16 + (l & 15);
                a[fm] = *(const short8_t*)(AsB + ((ra * 128 + kb) ^ ((ra & 7) << 4)));
            }
#pragma unroll
            for (int fn = 0; fn < 4; ++fn) {
                int nb = wc * 64 + fn * 16 + (l & 15);
                b[fn] = *(const short8_t*)(BsB + ((nb * 128 + kb) ^ ((nb & 7) << 4)));
            }
#pragma unroll
            for (int fm = 0; fm < 4; ++fm)
#pragma unroll
                for (int fn = 0; fn < 4; ++fn)
                    acc[fm][fn] = __builtin_amdgcn_mfma_f32_16x16x32_bf16(
                        a[fm], b[fn], acc[fm][fn], 0, 0, 0);
        }
        __syncthreads();
    }

#pragma unroll
    for (int fm = 0; fm < 4; ++fm) {
#pragma unroll
        for (int i = 0; i < 4; ++i) {
            int row = r0 + wr * 64 + fm * 16 + ((l >> 4) << 2) + i;
            if (row >= M) continue;
#pragma unroll
            for (int fn = 0; fn < 4; ++fn) {
                int col = wc * 64 + fn * 16 + (l & 15);
                int slice = col >> 5;
                H[(size_t)slice * SLICE_ELEMS + (size_t)row * 32 + (col & 31)] = f2b(acc[fm][fn][i]);
            }
        }
    }
}

// ---------------- sliced aggregation v6: degree-sorted, 8-lane group/node ----------------
// perm is degree-sorted: consecutive groups in a wave get near-equal round counts
// -> round loops are nearly wave-uniform (divergence fix). pbuf group stride 68
// words (16B-aligned, shifts banks by 4/group) -> conflict-free writes.
// Group fg processes perm[fg], perm[fg+16384], ... (spectrum-strided -> balanced).

__global__ __launch_bounds__(256) void k_agg_sliced(const unsigned short* __restrict__ H,
                                                    const int* __restrict__ rowstart,
                                                    const unsigned* __restrict__ csr4,
                                                    const int* __restrict__ perm,
                                                    const float* __restrict__ bias,
                                                    unsigned short* __restrict__ X,
                                                    float* __restrict__ gsum,
                                                    int write_out) {
    __shared__ unsigned pbuf[32 * 68];      // 32 groups x (2 x 32 + 4 pad)
    int slice = blockIdx.x & 7;
    int chunk = blockIdx.x >> 3;
    int g = threadIdx.x >> 3;        // 32 groups of 8 lanes
    int lane = threadIdx.x & 7;
    const char* Hb = (const char*)(H + (size_t)slice * SLICE_ELEMS) + (lane << 3);
    unsigned short* Xs = X + (size_t)slice * SLICE_ELEMS;
    int d0 = slice * 32 + lane * 4;
    float4 bb = *(const float4*)&bias[d0];
    float c0 = 0.f, c1 = 0.f, c2 = 0.f, c3 = 0.f;
    unsigned* ps = pbuf + g * 68;
    int fg = chunk * 32 + g;         // flat group id in [0, 16384)
    for (int idx = fg; idx < N_NODES; idx += TOTAL_GROUPS) {
        int n = perm[idx];
        int beg = rowstart[n], end = rowstart[n + 1];   // length multiple of 8
        float a0 = 0.f, a1 = 0.f, a2 = 0.f, a3 = 0.f;
        uint4 u = *(const uint4*)(csr4 + beg + (lane << 2));
        int r = 0;
        for (int e = beg; e < end; e += 32, ++r) {
            int en = (e + 32 < end) ? e + 32 : e;
            uint4 un = *(const uint4*)(csr4 + en + (lane << 2));
            unsigned* pb = ps + (r & 1) * 32;
            *(uint4*)(pb + (lane << 2)) = u;
#pragma unroll
            for (int s = 0; s < 4; ++s) {
                if (e + (s << 3) >= end) break;
#pragma unroll
                for (int i = 0; i < 8; ++i) {
                    unsigned p = pb[(s << 3) + i];
                    unsigned off = (p >> 16) << 6;                 // src * 64B
                    float nm = __uint_as_float(p << 16);           // bf16 norm
                    uint2 q = *(const uint2*)(Hb + off);           // 64B/group gather
                    a0 = fmaf(nm, __uint_as_float(q.x << 16), a0);
                    a1 = fmaf(nm, __uint_as_float(q.x & 0xFFFF0000u), a1);
                    a2 = fmaf(nm, __uint_as_float(q.y << 16), a2);
                    a3 = fmaf(nm, __uint_as_float(q.y & 0xFFFF0000u), a3);
                }
            }
            u = un;
        }
        float o0 = fmaxf(a0 + bb.x, 0.f);
        float o1 = fmaxf(a1 + bb.y, 0.f);
        float o2 = fmaxf(a2 + bb.z, 0.f);
        float o3 = fmaxf(a3 + bb.w, 0.f);
        if (write_out) {
            ushort4_t o; o.x = f2b(o0); o.y = f2b(o1); o.z = f2b(o2); o.w = f2b(o3);
            *(ushort4_t*)(Xs + (size_t)n * 32 + (lane << 2)) = o;
        }
        c0 += o0; c1 += o1; c2 += o2; c3 += o3;
    }
    if (gsum) {
        __shared__ float4 smr[256];
        int tid = threadIdx.x;
        smr[tid] = make_float4(c0, c1, c2, c3);
        __syncthreads();
#pragma unroll
        for (int off = 128; off >= 8; off >>= 1) {
            if (tid < off) {
                float4 a = smr[tid], b = smr[tid + off];
                smr[tid] = make_float4(a.x + b.x, a.y + b.y, a.z + b.z, a.w + b.w);
            }
            __syncthreads();
        }
        if (tid < 8) {   // tid == lane, d0 matches
            float4 v = smr[tid];
            atomicAdd(&gsum[d0], v.x);
            atomicAdd(&gsum[d0 + 1], v.y);
            atomicAdd(&gsum[d0 + 2], v.z);
            atomicAdd(&gsum[d0 + 3], v.w);
        }
    }
}

// ---------------- FC head (single block, fp32) ----------------

__global__ __launch_bounds__(256) void k_fc(const float* __restrict__ gsum,
                                            const float* __restrict__ fcW1,
                                            const float* __restrict__ fcb1,
                                            const float* __restrict__ fcW2,
                                            const float* __restrict__ fcb2,
                                            const float* __restrict__ fcW3,
                                            const float* __restrict__ fcb3,
                                            float* __restrict__ out) {
    __shared__ float g[DIM];
    __shared__ float h[DIM];
    int t = threadIdx.x;
    g[t] = fmaxf(gsum[t] * (1.0f / (float)N_NODES), 0.f);
    __syncthreads();
    float acc = fcb1[t];
    for (int k = 0; k < DIM; ++k) acc = fmaf(g[k], fcW1[k * DIM + t], acc);
    h[t] = fmaxf(acc, 0.f);
    __syncthreads();
    acc = fcb2[t];
    for (int k = 0; k < DIM; ++k) acc = fmaf(h[k], fcW2[k * DIM + t], acc);
    __syncthreads();
    g[t] = fmaxf(acc, 0.f);
    __syncthreads();
    if (t < ACT) {
        float o = fcb3[t];
        for (int k = 0; k < DIM; ++k) o = fmaf(g[k], fcW3[k * ACT + t], o);
        out[t] = o;
    }
}

// ---------------- launch ----------------

extern "C" void kernel_launch(void* const* d_in, const int* in_sizes, int n_in,
                              void* d_out, int out_size, void* d_ws, size_t ws_size,
                              hipStream_t stream) {
    const float* x    = (const float*)d_in[0];
    const int*   ei   = (const int*)d_in[1];
    const float* W1   = (const float*)d_in[2];
    const float* b1   = (const float*)d_in[3];
    const float* W2   = (const float*)d_in[4];
    const float* b2   = (const float*)d_in[5];
    const float* fcW1 = (const float*)d_in[6];
    const float* fcb1 = (const float*)d_in[7];
    const float* fcW2 = (const float*)d_in[8];
    const float* fcb2 = (const float*)d_in[9];
    const float* fcW3 = (const float*)d_in[10];
    const float* fcb3 = (const float*)d_in[11];
    float* out = (float*)d_out;

    char* w = (char*)d_ws;
    size_t o = 0;
#define CARVE(name, type, count) \
    type* name = (type*)(w + o); \
    o += (((size_t)(count) * sizeof(type)) + 255) & ~(size_t)255;
    CARVE(degi, int, N_NODES)
    CARVE(rowstart, int, N_NODES + 1)
    CARVE(fillpos, int, N_NODES)
    CARVE(dinv, float, N_NODES)
    CARVE(lexc, int, N_NODES)
    CARVE(btot, int, SCAN_NB)
    CARVE(bbase, int, SCAN_NB)
    CARVE(hist, int, NBINS)
    CARVE(histbase, int, NBINS)
    CARVE(perm, int, N_NODES)
    CARVE(csr4, unsigned, CSR_MAX)
    CARVE(gsum, float, DIM)
    CARVE(W1t, unsigned short, DIM * DIM)
    CARVE(W2t, unsigned short, DIM * DIM)
    CARVE(Hbuf, unsigned short, (size_t)N_NODES * DIM)  // bf16 sliced
    CARVE(Xbuf, unsigned short, (size_t)N_NODES * DIM)  // bf16 sliced
#undef CARVE

    hipMemsetAsync(gsum, 0, DIM * sizeof(float), stream);
    hipMemsetAsync(degi, 0, N_NODES * sizeof(int), stream);
    hipMemsetAsync(hist, 0, NBINS * sizeof(int), stream);
    hipMemsetAsync(csr4, 0, (size_t)CSR_MAX * sizeof(unsigned), stream);  // padding = (src0, +0.0)

    // weight prep
    k_cvt_wt2<<<512, 256, 0, stream>>>(W1, W2, W1t, W2t);

    // CSR build (rows padded to x8, 4B packed pairs) + degree-sorted perm
    k_deg_count<<<(N_EDGES + 255) / 256, 256, 0, stream>>>(ei, degi);
    k_hist<<<SCAN_NB, 256, 0, stream>>>(degi, hist);
    k_scan_local<<<SCAN_NB, SCAN_B, 0, stream>>>(degi, lexc, btot);
    k_scan_tops<<<1, SCAN_B, 0, stream>>>(btot, bbase, rowstart, hist, histbase);
    k_perm<<<SCAN_NB, 256, 0, stream>>>(degi, histbase, perm);
    k_scan_apply<<<SCAN_NB, SCAN_B, 0, stream>>>(degi, lexc, bbase, rowstart, fillpos,
                                                 dinv, csr4);
    k_fill_edge<<<(N_EDGES + 255) / 256, 256, 0, stream>>>(ei, dinv, fillpos, csr4);

    // layer 1 (GEMM converts x fp32->bf16 in-staging)
    int gemm_grid = (N_NODES + 127) / 128;   // 391
    k_gemm_mfma<1><<<gemm_grid, 512, 0, stream>>>(x, W1t, Hbuf, N_NODES);
    k_agg_sliced<<<8 * AGG_CHUNKS, 256, 0, stream>>>(Hbuf, rowstart, csr4, perm, b1,
                                                     Xbuf, (float*)nullptr, 1);
    // layer 2 (agg fuses mean-pool column sum, no X write)
    k_gemm_mfma<0><<<gemm_grid, 512, 0, stream>>>(Xbuf, W2t, Hbuf, N_NODES);
    k_agg_sliced<<<8 * AGG_CHUNKS, 256, 0, stream>>>(Hbuf, rowstart, csr4, perm, b2,
                                                     Xbuf, gsum, 0);

    // head
    k_fc<<<1, 256, 0, stream>>>(gsum, fcW1, fcb1, fcW2, fcb2, fcW3, fcb3, out);
}

// Round 13
// 281.478 us; speedup vs baseline: 3.6440x; 3.6440x over previous
//
#include <hip/hip_runtime.h>

#define N_NODES 50000
#define N_EDGES 800000
#define DIM 256
#define ACT 64
#define SCAN_B 256
#define SCAN_NB ((N_NODES + SCAN_B - 1) / SCAN_B)   // 196
#define SLICE_ELEMS ((size_t)N_NODES * 32)          // elems per 32-dim slice
#define AGG_CHUNKS 512
#define TOTAL_GROUPS (AGG_CHUNKS * 32)              // 16384 groups per slice
#define CSR_MAX (N_EDGES + 8 * N_NODES + 64)        // padded-to-8 CSR + overread slack
#define NBINS 16
#define NBB (NBINS * SCAN_NB)                       // 3136 (bin,block) cells

typedef __attribute__((ext_vector_type(8))) short short8_t;
typedef __attribute__((ext_vector_type(4))) float f32x4;
typedef __attribute__((ext_vector_type(4))) unsigned short ushort4_t;

__device__ __forceinline__ unsigned short f2b(float x) {   // f32 -> bf16 RNE
    unsigned u = __float_as_uint(x);
    unsigned r = u + 0x7FFFu + ((u >> 16) & 1u);
    return (unsigned short)(r >> 16);
}

__device__ __forceinline__ int deg_bin(int deg) {
    int rounds = ((deg + 8) & ~7) >> 3;   // padded slots / 8
    return (rounds > NBINS - 1) ? NBINS - 1 : rounds;
}

// ---------------- weight transpose + convert ----------------

__global__ __launch_bounds__(256) void k_cvt_wt2(const float* __restrict__ W1,
                                                 const float* __restrict__ W2,
                                                 unsigned short* __restrict__ W1t,
                                                 unsigned short* __restrict__ W2t) {
    int b = blockIdx.x;
    const float* W = (b < 256) ? W1 : W2;
    unsigned short* Wt = (b < 256) ? W1t : W2t;
    int i = (b & 255) * 256 + threadIdx.x;
    int k = i >> 8, n = i & 255;
    Wt[n * DIM + k] = f2b(W[k * DIM + n]);
}

// ---------------- degree (degi pre-zeroed; self-loop accounted as +1 in scan) ----------------

__global__ void k_deg_count(const int* __restrict__ ei, int* degi) {
    int e = blockIdx.x * blockDim.x + threadIdx.x;
    if (e < N_EDGES) atomicAdd(&degi[ei[N_EDGES + e]], 1);  // dst row
}

// ---------------- contention-free counting sort by round count ----------------
// pass 1: per-block LDS histogram + per-node local rank (stable within block)

__global__ __launch_bounds__(256) void k_hist_rank(const int* __restrict__ degi,
                                                   int* blockbin,
                                                   unsigned char* lrank) {
    __shared__ int lh[NBINS];
    int t = threadIdx.x;
    if (t < NBINS) lh[t] = 0;
    __syncthreads();
    int i = blockIdx.x * 256 + t;
    if (i < N_NODES) {
        int bin = deg_bin(degi[i]);
        lrank[i] = (unsigned char)atomicAdd(&lh[bin], 1);   // LDS atomic: block-local
    }
    __syncthreads();
    if (t < NBINS) blockbin[t * SCAN_NB + blockIdx.x] = lh[t];   // bin-major
}

// pass 2: one-block exclusive scan over the 3136 (bin,block) counts
__global__ __launch_bounds__(256) void k_scan_bins(const int* __restrict__ blockbin,
                                                   int* blockbase) {
    __shared__ int sm[256];
    int t = threadIdx.x;
    const int CH = (NBB + 255) / 256;   // 13
    int s0 = t * CH;
    int s1 = s0 + CH; if (s1 > NBB) s1 = NBB;
    int s = 0;
    for (int i = s0; i < s1; ++i) s += blockbin[i];
    sm[t] = s;
    __syncthreads();
#pragma unroll
    for (int off = 1; off < 256; off <<= 1) {
        int u = (t >= off) ? sm[t - off] : 0;
        __syncthreads();
        sm[t] += u;
        __syncthreads();
    }
    int base = sm[t] - s;
    for (int i = s0; i < s1; ++i) { int v = blockbin[i]; blockbase[i] = base; base += v; }
}

// pass 3: scatter node ids into degree-sorted perm
__global__ __launch_bounds__(256) void k_perm_apply(const int* __restrict__ degi,
                                                    const int* __restrict__ blockbase,
                                                    const unsigned char* __restrict__ lrank,
                                                    int* perm) {
    int i = blockIdx.x * 256 + threadIdx.x;
    if (i >= N_NODES) return;
    int bin = deg_bin(degi[i]);
    perm[blockbase[bin * SCAN_NB + blockIdx.x] + lrank[i]] = i;
}

// ---------------- hierarchical exclusive scan over PADDED row lengths ----------------
// padded_len(i) = roundup8(degi[i] + 1); padding slots stay 0 = (src=0, norm=+0.0bf16).

__global__ __launch_bounds__(SCAN_B) void k_scan_local(const int* __restrict__ degi,
                                                       int* lexc, int* btot) {
    __shared__ int sm[SCAN_B];
    int t = threadIdx.x;
    int i = blockIdx.x * SCAN_B + t;
    int v = (i < N_NODES) ? ((degi[i] + 8) & ~7) : 0;   // roundup8(deg+1)
    sm[t] = v;
    __syncthreads();
#pragma unroll
    for (int off = 1; off < SCAN_B; off <<= 1) {
        int u = (t >= off) ? sm[t - off] : 0;
        __syncthreads();
        sm[t] += u;
        __syncthreads();
    }
    if (i < N_NODES) lexc[i] = sm[t] - v;
    if (t == SCAN_B - 1) btot[blockIdx.x] = sm[t];
}

__global__ __launch_bounds__(SCAN_B) void k_scan_tops(const int* __restrict__ btot,
                                                      int* bbase, int* rowstart) {
    __shared__ int sm[SCAN_B];
    int t = threadIdx.x;
    int v = (t < SCAN_NB) ? btot[t] : 0;
    sm[t] = v;
    __syncthreads();
#pragma unroll
    for (int off = 1; off < SCAN_B; off <<= 1) {
        int u = (t >= off) ? sm[t - off] : 0;
        __syncthreads();
        sm[t] += u;
        __syncthreads();
    }
    if (t < SCAN_NB) bbase[t] = sm[t] - v;
    if (t == SCAN_NB - 1) rowstart[N_NODES] = sm[t];
}

// csr4 entry: (src << 16) | bf16(norm)   -- src < 65536, norm in (0,1]
__global__ __launch_bounds__(SCAN_B) void k_scan_apply(const int* __restrict__ degi,
                                                       const int* __restrict__ lexc,
                                                       const int* __restrict__ bbase,
                                                       int* rowstart, int* fillpos,
                                                       float* dinv, unsigned* csr4) {
    int i = blockIdx.x * SCAN_B + threadIdx.x;
    if (i >= N_NODES) return;
    int rs = bbase[blockIdx.x] + lexc[i];
    rowstart[i] = rs;
    int d = degi[i] + 1;
    float di = rsqrtf((float)d);
    dinv[i] = di;
    csr4[rs] = ((unsigned)i << 16) | f2b(di * di);   // self-loop first in row
    fillpos[i] = rs + 1;
}

__global__ void k_fill_edge(const int* __restrict__ ei,
                            const float* __restrict__ dinv, int* fillpos,
                            unsigned* csr4) {
    int e = blockIdx.x * blockDim.x + threadIdx.x;
    if (e < N_EDGES) {
        int s = ei[e];
        int d = ei[N_EDGES + e];
        int p = atomicAdd(&fillpos[d], 1);
        csr4[p] = ((unsigned)s << 16) | f2b(dinv[s] * dinv[d]);
    }
}

// ---------------- bf16 MFMA GEMM: H = A @ Wt^T  (H SLICED; A fp32 row-major or sliced bf16) --

template <int AFP32>
__global__ __launch_bounds__(512) void k_gemm_mfma(const void* __restrict__ Ap,
                                                   const unsigned short* __restrict__ Wt,
                                                   unsigned short* __restrict__ H,
                                                   int M) {
    __shared__ char lds[49152];          // As 128x64 bf16 (16KB) + Bs 256x64 bf16 (32KB)
    char* AsB = lds;
    char* BsB = lds + 16384;

    int tid = threadIdx.x;
    int w = tid >> 6;
    int l = tid & 63;
    int wr = w >> 2, wc = w & 3;
    int r0 = blockIdx.x * 128;

    f32x4 acc[4][4];
#pragma unroll
    for (int i = 0; i < 4; ++i)
#pragma unroll
        for (int j = 0; j < 4; ++j) acc[i][j] = (f32x4)(0.f);

    for (int kt = 0; kt < 4; ++kt) {
        int k0 = kt * 64;
#pragma unroll
        for (int i = 0; i < 2; ++i) {
            int c = tid + i * 512;
            int row = c >> 3, kc = c & 7;
            int gg = r0 + row; if (gg >= M) gg = M - 1;
            short8_t v;
            if (AFP32) {
                const float* A = (const float*)Ap;
                const float4* src = (const float4*)(A + (size_t)gg * DIM + k0 + kc * 8);
                float4 f0 = src[0], f1 = src[1];
                v[0] = (short)f2b(f0.x); v[1] = (short)f2b(f0.y);
                v[2] = (short)f2b(f0.z); v[3] = (short)f2b(f0.w);
                v[4] = (short)f2b(f1.x); v[5] = (short)f2b(f1.y);
                v[6] = (short)f2b(f1.z); v[7] = (short)f2b(f1.w);
            } else {
                const unsigned short* A = (const unsigned short*)Ap;
                int k = k0 + kc * 8;
                int slice = k >> 5, within = k & 31;
                v = *(const short8_t*)(A + (size_t)slice * SLICE_ELEMS + (size_t)gg * 32 + within);
            }
            int off = (row * 128 + kc * 16) ^ ((row & 7) << 4);
            *(short8_t*)(AsB + off) = v;
        }
#pragma unroll
        for (int i = 0; i < 4; ++i) {
            int c = tid + i * 512;
            int n = c >> 3, kc = c & 7;
            short8_t v = *(const short8_t*)(Wt + n * DIM + k0 + kc * 8);
            int off = (n * 128 + kc * 16) ^ ((n & 7) << 4);
            *(short8_t*)(BsB + off) = v;
        }
        __syncthreads();

#pragma unroll
        for (int kf = 0; kf < 2; ++kf) {
            int kb = kf * 64 + (l >> 4) * 16;
            short8_t a[4], b[4];
#pragma unroll
            for (int fm = 0; fm < 4; ++fm) {
                int ra = wr * 64 + fm * 16 + (l & 15);
                a[fm] = *(const short8_t*)(AsB + ((ra * 128 + kb) ^ ((ra & 7) << 4)));
            }
#pragma unroll
            for (int fn = 0; fn < 4; ++fn) {
                int nb = wc * 64 + fn * 16 + (l & 15);
                b[fn] = *(const short8_t*)(BsB + ((nb * 128 + kb) ^ ((nb & 7) << 4)));
            }
#pragma unroll
            for (int fm = 0; fm < 4; ++fm)
#pragma unroll
                for (int fn = 0; fn < 4; ++fn)
                    acc[fm][fn] = __builtin_amdgcn_mfma_f32_16x16x32_bf16(
                        a[fm], b[fn], acc[fm][fn], 0, 0, 0);
        }
        __syncthreads();
    }

#pragma unroll
    for (int fm = 0; fm < 4; ++fm) {
#pragma unroll
        for (int i = 0; i < 4; ++i) {
            int row = r0 + wr * 64 + fm * 16 + ((l >> 4) << 2) + i;
            if (row >= M) continue;
#pragma unroll
            for (int fn = 0; fn < 4; ++fn) {
                int col = wc * 64 + fn * 16 + (l & 15);
                int slice = col >> 5;
                H[(size_t)slice * SLICE_ELEMS + (size_t)row * 32 + (col & 31)] = f2b(acc[fm][fn][i]);
            }
        }
    }
}

// ---------------- sliced aggregation v6: degree-sorted, 8-lane group/node ----------------
// perm is degree-sorted: consecutive groups in a wave get near-equal round counts
// -> round loops nearly wave-uniform. pbuf group stride 68 words -> conflict-free.

__global__ __launch_bounds__(256) void k_agg_sliced(const unsigned short* __restrict__ H,
                                                    const int* __restrict__ rowstart,
                                                    const unsigned* __restrict__ csr4,
                                                    const int* __restrict__ perm,
                                                    const float* __restrict__ bias,
                                                    unsigned short* __restrict__ X,
                                                    float* __restrict__ gsum,
                                                    int write_out) {
    __shared__ unsigned pbuf[32 * 68];      // 32 groups x (2 x 32 + 4 pad)
    int slice = blockIdx.x & 7;
    int chunk = blockIdx.x >> 3;
    int g = threadIdx.x >> 3;        // 32 groups of 8 lanes
    int lane = threadIdx.x & 7;
    const char* Hb = (const char*)(H + (size_t)slice * SLICE_ELEMS) + (lane << 3);
    unsigned short* Xs = X + (size_t)slice * SLICE_ELEMS;
    int d0 = slice * 32 + lane * 4;
    float4 bb = *(const float4*)&bias[d0];
    float c0 = 0.f, c1 = 0.f, c2 = 0.f, c3 = 0.f;
    unsigned* ps = pbuf + g * 68;
    int fg = chunk * 32 + g;         // flat group id in [0, 16384)
    for (int idx = fg; idx < N_NODES; idx += TOTAL_GROUPS) {
        int n = perm[idx];
        int beg = rowstart[n], end = rowstart[n + 1];   // length multiple of 8
        float a0 = 0.f, a1 = 0.f, a2 = 0.f, a3 = 0.f;
        uint4 u = *(const uint4*)(csr4 + beg + (lane << 2));
        int r = 0;
        for (int e = beg; e < end; e += 32, ++r) {
            int en = (e + 32 < end) ? e + 32 : e;
            uint4 un = *(const uint4*)(csr4 + en + (lane << 2));
            unsigned* pb = ps + (r & 1) * 32;
            *(uint4*)(pb + (lane << 2)) = u;
#pragma unroll
            for (int s = 0; s < 4; ++s) {
                if (e + (s << 3) >= end) break;
#pragma unroll
                for (int i = 0; i < 8; ++i) {
                    unsigned p = pb[(s << 3) + i];
                    unsigned off = (p >> 16) << 6;                 // src * 64B
                    float nm = __uint_as_float(p << 16);           // bf16 norm
                    uint2 q = *(const uint2*)(Hb + off);           // 64B/group gather
                    a0 = fmaf(nm, __uint_as_float(q.x << 16), a0);
                    a1 = fmaf(nm, __uint_as_float(q.x & 0xFFFF0000u), a1);
                    a2 = fmaf(nm, __uint_as_float(q.y << 16), a2);
                    a3 = fmaf(nm, __uint_as_float(q.y & 0xFFFF0000u), a3);
                }
            }
            u = un;
        }
        float o0 = fmaxf(a0 + bb.x, 0.f);
        float o1 = fmaxf(a1 + bb.y, 0.f);
        float o2 = fmaxf(a2 + bb.z, 0.f);
        float o3 = fmaxf(a3 + bb.w, 0.f);
        if (write_out) {
            ushort4_t o; o.x = f2b(o0); o.y = f2b(o1); o.z = f2b(o2); o.w = f2b(o3);
            *(ushort4_t*)(Xs + (size_t)n * 32 + (lane << 2)) = o;
        }
        c0 += o0; c1 += o1; c2 += o2; c3 += o3;
    }
    if (gsum) {
        __shared__ float4 smr[256];
        int tid = threadIdx.x;
        smr[tid] = make_float4(c0, c1, c2, c3);
        __syncthreads();
#pragma unroll
        for (int off = 128; off >= 8; off >>= 1) {
            if (tid < off) {
                float4 a = smr[tid], b = smr[tid + off];
                smr[tid] = make_float4(a.x + b.x, a.y + b.y, a.z + b.z, a.w + b.w);
            }
            __syncthreads();
        }
        if (tid < 8) {   // tid == lane, d0 matches
            float4 v = smr[tid];
            atomicAdd(&gsum[d0], v.x);
            atomicAdd(&gsum[d0 + 1], v.y);
            atomicAdd(&gsum[d0 + 2], v.z);
            atomicAdd(&gsum[d0 + 3], v.w);
        }
    }
}

// ---------------- FC head (single block, fp32) ----------------

__global__ __launch_bounds__(256) void k_fc(const float* __restrict__ gsum,
                                            const float* __restrict__ fcW1,
                                            const float* __restrict__ fcb1,
                                            const float* __restrict__ fcW2,
                                            const float* __restrict__ fcb2,
                                            const float* __restrict__ fcW3,
                                            const float* __restrict__ fcb3,
                                            float* __restrict__ out) {
    __shared__ float g[DIM];
    __shared__ float h[DIM];
    int t = threadIdx.x;
    g[t] = fmaxf(gsum[t] * (1.0f / (float)N_NODES), 0.f);
    __syncthreads();
    float acc = fcb1[t];
    for (int k = 0; k < DIM; ++k) acc = fmaf(g[k], fcW1[k * DIM + t], acc);
    h[t] = fmaxf(acc, 0.f);
    __syncthreads();
    acc = fcb2[t];
    for (int k = 0; k < DIM; ++k) acc = fmaf(h[k], fcW2[k * DIM + t], acc);
    __syncthreads();
    g[t] = fmaxf(acc, 0.f);
    __syncthreads();
    if (t < ACT) {
        float o = fcb3[t];
        for (int k = 0; k < DIM; ++k) o = fmaf(g[k], fcW3[k * ACT + t], o);
        out[t] = o;
    }
}

// ---------------- launch ----------------

extern "C" void kernel_launch(void* const* d_in, const int* in_sizes, int n_in,
                              void* d_out, int out_size, void* d_ws, size_t ws_size,
                              hipStream_t stream) {
    const float* x    = (const float*)d_in[0];
    const int*   ei   = (const int*)d_in[1];
    const float* W1   = (const float*)d_in[2];
    const float* b1   = (const float*)d_in[3];
    const float* W2   = (const float*)d_in[4];
    const float* b2   = (const float*)d_in[5];
    const float* fcW1 = (const float*)d_in[6];
    const float* fcb1 = (const float*)d_in[7];
    const float* fcW2 = (const float*)d_in[8];
    const float* fcb2 = (const float*)d_in[9];
    const float* fcW3 = (const float*)d_in[10];
    const float* fcb3 = (const float*)d_in[11];
    float* out = (float*)d_out;

    char* w = (char*)d_ws;
    size_t o = 0;
#define CARVE(name, type, count) \
    type* name = (type*)(w + o); \
    o += (((size_t)(count) * sizeof(type)) + 255) & ~(size_t)255;
    CARVE(degi, int, N_NODES)
    CARVE(rowstart, int, N_NODES + 1)
    CARVE(fillpos, int, N_NODES)
    CARVE(dinv, float, N_NODES)
    CARVE(lexc, int, N_NODES)
    CARVE(btot, int, SCAN_NB)
    CARVE(bbase, int, SCAN_NB)
    CARVE(blockbin, int, NBB)
    CARVE(blockbase, int, NBB)
    CARVE(perm, int, N_NODES)
    CARVE(lrank, unsigned char, N_NODES)
    CARVE(csr4, unsigned, CSR_MAX)
    CARVE(gsum, float, DIM)
    CARVE(W1t, unsigned short, DIM * DIM)
    CARVE(W2t, unsigned short, DIM * DIM)
    CARVE(Hbuf, unsigned short, (size_t)N_NODES * DIM)  // bf16 sliced
    CARVE(Xbuf, unsigned short, (size_t)N_NODES * DIM)  // bf16 sliced
#undef CARVE

    hipMemsetAsync(gsum, 0, DIM * sizeof(float), stream);
    hipMemsetAsync(degi, 0, N_NODES * sizeof(int), stream);
    hipMemsetAsync(csr4, 0, (size_t)CSR_MAX * sizeof(unsigned), stream);  // padding = (src0, +0.0)

    // weight prep
    k_cvt_wt2<<<512, 256, 0, stream>>>(W1, W2, W1t, W2t);

    // CSR build (rows padded to x8, 4B packed pairs) + contention-free degree sort
    k_deg_count<<<(N_EDGES + 255) / 256, 256, 0, stream>>>(ei, degi);
    k_hist_rank<<<SCAN_NB, 256, 0, stream>>>(degi, blockbin, lrank);
    k_scan_bins<<<1, 256, 0, stream>>>(blockbin, blockbase);
    k_perm_apply<<<SCAN_NB, 256, 0, stream>>>(degi, blockbase, lrank, perm);
    k_scan_local<<<SCAN_NB, SCAN_B, 0, stream>>>(degi, lexc, btot);
    k_scan_tops<<<1, SCAN_B, 0, stream>>>(btot, bbase, rowstart);
    k_scan_apply<<<SCAN_NB, SCAN_B, 0, stream>>>(degi, lexc, bbase, rowstart, fillpos,
                                                 dinv, csr4);
    k_fill_edge<<<(N_EDGES + 255) / 256, 256, 0, stream>>>(ei, dinv, fillpos, csr4);

    // layer 1 (GEMM converts x fp32->bf16 in-staging)
    int gemm_grid = (N_NODES + 127) / 128;   // 391
    k_gemm_mfma<1><<<gemm_grid, 512, 0, stream>>>(x, W1t, Hbuf, N_NODES);
    k_agg_sliced<<<8 * AGG_CHUNKS, 256, 0, stream>>>(Hbuf, rowstart, csr4, perm, b1,
                                                     Xbuf, (float*)nullptr, 1);
    // layer 2 (agg fuses mean-pool column sum, no X write)
    k_gemm_mfma<0><<<gemm_grid, 512, 0, stream>>>(Xbuf, W2t, Hbuf, N_NODES);
    k_agg_sliced<<<8 * AGG_CHUNKS, 256, 0, stream>>>(Hbuf, rowstart, csr4, perm, b2,
                                                     Xbuf, gsum, 0);

    // head
    k_fc<<<1, 256, 0, stream>>>(gsum, fcW1, fcb1, fcW2, fcb2, fcW3, fcb3, out);
}

// Round 14
// 281.383 us; speedup vs baseline: 3.6453x; 1.0003x over previous
//
#include <hip/hip_runtime.h>

#define N_NODES 50000
#define N_EDGES 800000
#define DIM 256
#define ACT 64
#define SCAN_B 256
#define SCAN_NB ((N_NODES + SCAN_B - 1) / SCAN_B)   // 196
#define SLICE_ELEMS ((size_t)N_NODES * 32)          // elems per 32-dim slice
#define AGG_CHUNKS 512
#define TOTAL_GROUPS (AGG_CHUNKS * 32)              // 16384 groups per slice
#define CSR_MAX (N_EDGES + 16 * N_NODES + 64)       // padded-to-16 CSR + overread slack
#define NBINS 16
#define NBB (NBINS * SCAN_NB)                       // 3136 (bin,block) cells

typedef __attribute__((ext_vector_type(8))) short short8_t;
typedef __attribute__((ext_vector_type(4))) float f32x4;
typedef __attribute__((ext_vector_type(4))) unsigned short ushort4_t;

__device__ __forceinline__ unsigned short f2b(float x) {   // f32 -> bf16 RNE
    unsigned u = __float_as_uint(x);
    unsigned r = u + 0x7FFFu + ((u >> 16) & 1u);
    return (unsigned short)(r >> 16);
}

__device__ __forceinline__ int deg_bin(int deg) {
    int rounds = ((deg + 16) & ~15) >> 4;   // padded-16 slots / 16
    return (rounds > NBINS - 1) ? NBINS - 1 : rounds;
}

// ---------------- weight transpose + convert ----------------

__global__ __launch_bounds__(256) void k_cvt_wt2(const float* __restrict__ W1,
                                                 const float* __restrict__ W2,
                                                 unsigned short* __restrict__ W1t,
                                                 unsigned short* __restrict__ W2t) {
    int b = blockIdx.x;
    const float* W = (b < 256) ? W1 : W2;
    unsigned short* Wt = (b < 256) ? W1t : W2t;
    int i = (b & 255) * 256 + threadIdx.x;
    int k = i >> 8, n = i & 255;
    Wt[n * DIM + k] = f2b(W[k * DIM + n]);
}

// ---------------- degree (degi pre-zeroed; self-loop accounted as +1 in scan) ----------------

__global__ void k_deg_count(const int* __restrict__ ei, int* degi) {
    int e = blockIdx.x * blockDim.x + threadIdx.x;
    if (e < N_EDGES) atomicAdd(&degi[ei[N_EDGES + e]], 1);  // dst row
}

// ---------------- contention-free counting sort by round count ----------------

__global__ __launch_bounds__(256) void k_hist_rank(const int* __restrict__ degi,
                                                   int* blockbin,
                                                   unsigned char* lrank) {
    __shared__ int lh[NBINS];
    int t = threadIdx.x;
    if (t < NBINS) lh[t] = 0;
    __syncthreads();
    int i = blockIdx.x * 256 + t;
    if (i < N_NODES) {
        int bin = deg_bin(degi[i]);
        lrank[i] = (unsigned char)atomicAdd(&lh[bin], 1);   // LDS atomic: block-local
    }
    __syncthreads();
    if (t < NBINS) blockbin[t * SCAN_NB + blockIdx.x] = lh[t];   // bin-major
}

__global__ __launch_bounds__(256) void k_scan_bins(const int* __restrict__ blockbin,
                                                   int* blockbase) {
    __shared__ int sm[256];
    int t = threadIdx.x;
    const int CH = (NBB + 255) / 256;   // 13
    int s0 = t * CH;
    int s1 = s0 + CH; if (s1 > NBB) s1 = NBB;
    int s = 0;
    for (int i = s0; i < s1; ++i) s += blockbin[i];
    sm[t] = s;
    __syncthreads();
#pragma unroll
    for (int off = 1; off < 256; off <<= 1) {
        int u = (t >= off) ? sm[t - off] : 0;
        __syncthreads();
        sm[t] += u;
        __syncthreads();
    }
    int base = sm[t] - s;
    for (int i = s0; i < s1; ++i) { int v = blockbin[i]; blockbase[i] = base; base += v; }
}

__global__ __launch_bounds__(256) void k_perm_apply(const int* __restrict__ degi,
                                                    const int* __restrict__ blockbase,
                                                    const unsigned char* __restrict__ lrank,
                                                    int* perm) {
    int i = blockIdx.x * 256 + threadIdx.x;
    if (i >= N_NODES) return;
    int bin = deg_bin(degi[i]);
    perm[blockbase[bin * SCAN_NB + blockIdx.x] + lrank[i]] = i;
}

// ---------------- scan over PADDED row lengths in SORTED order ----------------
// padded_len = roundup16(deg+1); rowstart indexed by SORTED position ->
// csr4 is physically laid out in degree-sorted order (streaming locality in agg).

__global__ __launch_bounds__(SCAN_B) void k_scan_local(const int* __restrict__ degi,
                                                       const int* __restrict__ perm,
                                                       int* lexc, int* btot) {
    __shared__ int sm[SCAN_B];
    int t = threadIdx.x;
    int i = blockIdx.x * SCAN_B + t;
    int v = (i < N_NODES) ? ((degi[perm[i]] + 16) & ~15) : 0;   // roundup16(deg+1)
    sm[t] = v;
    __syncthreads();
#pragma unroll
    for (int off = 1; off < SCAN_B; off <<= 1) {
        int u = (t >= off) ? sm[t - off] : 0;
        __syncthreads();
        sm[t] += u;
        __syncthreads();
    }
    if (i < N_NODES) lexc[i] = sm[t] - v;
    if (t == SCAN_B - 1) btot[blockIdx.x] = sm[t];
}

__global__ __launch_bounds__(SCAN_B) void k_scan_tops(const int* __restrict__ btot,
                                                      int* bbase, int* rowstart) {
    __shared__ int sm[SCAN_B];
    int t = threadIdx.x;
    int v = (t < SCAN_NB) ? btot[t] : 0;
    sm[t] = v;
    __syncthreads();
#pragma unroll
    for (int off = 1; off < SCAN_B; off <<= 1) {
        int u = (t >= off) ? sm[t - off] : 0;
        __syncthreads();
        sm[t] += u;
        __syncthreads();
    }
    if (t < SCAN_NB) bbase[t] = sm[t] - v;
    if (t == SCAN_NB - 1) rowstart[N_NODES] = sm[t];
}

// csr4 entry: (src << 16) | bf16(norm). Sorted position i -> node perm[i].
__global__ __launch_bounds__(SCAN_B) void k_scan_apply(const int* __restrict__ degi,
                                                       const int* __restrict__ perm,
                                                       const int* __restrict__ lexc,
                                                       const int* __restrict__ bbase,
                                                       int* rowstart, int* fillpos,
                                                       float* dinv, unsigned* csr4) {
    int i = blockIdx.x * SCAN_B + threadIdx.x;
    if (i >= N_NODES) return;
    int rs = bbase[blockIdx.x] + lexc[i];
    rowstart[i] = rs;                    // sorted-order rowstart
    int n = perm[i];
    int d = degi[n] + 1;
    float di = rsqrtf((float)d);
    dinv[n] = di;
    csr4[rs] = ((unsigned)n << 16) | f2b(di * di);   // self-loop first in row
    fillpos[n] = rs + 1;                 // fill positions indexed by NODE
}

__global__ void k_fill_edge(const int* __restrict__ ei,
                            const float* __restrict__ dinv, int* fillpos,
                            unsigned* csr4) {
    int e = blockIdx.x * blockDim.x + threadIdx.x;
    if (e < N_EDGES) {
        int s = ei[e];
        int d = ei[N_EDGES + e];
        int p = atomicAdd(&fillpos[d], 1);
        csr4[p] = ((unsigned)s << 16) | f2b(dinv[s] * dinv[d]);
    }
}

// ---------------- bf16 MFMA GEMM: H = A @ Wt^T  (H SLICED; A fp32 row-major or sliced bf16) --

template <int AFP32>
__global__ __launch_bounds__(512) void k_gemm_mfma(const void* __restrict__ Ap,
                                                   const unsigned short* __restrict__ Wt,
                                                   unsigned short* __restrict__ H,
                                                   int M) {
    __shared__ char lds[49152];          // As 128x64 bf16 (16KB) + Bs 256x64 bf16 (32KB)
    char* AsB = lds;
    char* BsB = lds + 16384;

    int tid = threadIdx.x;
    int w = tid >> 6;
    int l = tid & 63;
    int wr = w >> 2, wc = w & 3;
    int r0 = blockIdx.x * 128;

    f32x4 acc[4][4];
#pragma unroll
    for (int i = 0; i < 4; ++i)
#pragma unroll
        for (int j = 0; j < 4; ++j) acc[i][j] = (f32x4)(0.f);

    for (int kt = 0; kt < 4; ++kt) {
        int k0 = kt * 64;
#pragma unroll
        for (int i = 0; i < 2; ++i) {
            int c = tid + i * 512;
            int row = c >> 3, kc = c & 7;
            int gg = r0 + row; if (gg >= M) gg = M - 1;
            short8_t v;
            if (AFP32) {
                const float* A = (const float*)Ap;
                const float4* src = (const float4*)(A + (size_t)gg * DIM + k0 + kc * 8);
                float4 f0 = src[0], f1 = src[1];
                v[0] = (short)f2b(f0.x); v[1] = (short)f2b(f0.y);
                v[2] = (short)f2b(f0.z); v[3] = (short)f2b(f0.w);
                v[4] = (short)f2b(f1.x); v[5] = (short)f2b(f1.y);
                v[6] = (short)f2b(f1.z); v[7] = (short)f2b(f1.w);
            } else {
                const unsigned short* A = (const unsigned short*)Ap;
                int k = k0 + kc * 8;
                int slice = k >> 5, within = k & 31;
                v = *(const short8_t*)(A + (size_t)slice * SLICE_ELEMS + (size_t)gg * 32 + within);
            }
            int off = (row * 128 + kc * 16) ^ ((row & 7) << 4);
            *(short8_t*)(AsB + off) = v;
        }
#pragma unroll
        for (int i = 0; i < 4; ++i) {
            int c = tid + i * 512;
            int n = c >> 3, kc = c & 7;
            short8_t v = *(const short8_t*)(Wt + n * DIM + k0 + kc * 8);
            int off = (n * 128 + kc * 16) ^ ((n & 7) << 4);
            *(short8_t*)(BsB + off) = v;
        }
        __syncthreads();

#pragma unroll
        for (int kf = 0; kf < 2; ++kf) {
            int kb = kf * 64 + (l >> 4) * 16;
            short8_t a[4], b[4];
#pragma unroll
            for (int fm = 0; fm < 4; ++fm) {
                int ra = wr * 64 + fm * 16 + (l & 15);
                a[fm] = *(const short8_t*)(AsB + ((ra * 128 + kb) ^ ((ra & 7) << 4)));
            }
#pragma unroll
            for (int fn = 0; fn < 4; ++fn) {
                int nb = wc * 64 + fn * 16 + (l & 15);
                b[fn] = *(const short8_t*)(BsB + ((nb * 128 + kb) ^ ((nb & 7) << 4)));
            }
#pragma unroll
            for (int fm = 0; fm < 4; ++fm)
#pragma unroll
                for (int fn = 0; fn < 4; ++fn)
                    acc[fm][fn] = __builtin_amdgcn_mfma_f32_16x16x32_bf16(
                        a[fm], b[fn], acc[fm][fn], 0, 0, 0);
        }
        __syncthreads();
    }

#pragma unroll
    for (int fm = 0; fm < 4; ++fm) {
#pragma unroll
        for (int i = 0; i < 4; ++i) {
            int row = r0 + wr * 64 + fm * 16 + ((l >> 4) << 2) + i;
            if (row >= M) continue;
#pragma unroll
            for (int fn = 0; fn < 4; ++fn) {
                int col = wc * 64 + fn * 16 + (l & 15);
                int slice = col >> 5;
                H[(size_t)slice * SLICE_ELEMS + (size_t)row * 32 + (col & 31)] = f2b(acc[fm][fn][i]);
            }
        }
    }
}

// ---------------- sliced aggregation v7: sorted CSR + 16-deep register-batched gathers ----
// CSR physically in degree-sorted order: rowstart[idx] contiguous, csr4 streamed.
// Per 32-slot superround: stage via uint4+ds_write (dbuf); 2 batches of 16:
// read 16 pairs to regs -> issue 16 INDEPENDENT gathers into uint2 q[16]
// (static-indexed, stays in VGPR) -> 64 fma. ~16 gathers in flight per wave.

__global__ __launch_bounds__(256) void k_agg_sliced(const unsigned short* __restrict__ H,
                                                    const int* __restrict__ rowstart,
                                                    const unsigned* __restrict__ csr4,
                                                    const int* __restrict__ perm,
                                                    const float* __restrict__ bias,
                                                    unsigned short* __restrict__ X,
                                                    float* __restrict__ gsum,
                                                    int write_out) {
    __shared__ unsigned pbuf[32 * 68];      // 32 groups x (2 x 32 + 4 pad)
    int slice = blockIdx.x & 7;
    int chunk = blockIdx.x >> 3;
    int g = threadIdx.x >> 3;        // 32 groups of 8 lanes
    int lane = threadIdx.x & 7;
    const char* Hb = (const char*)(H + (size_t)slice * SLICE_ELEMS) + (lane << 3);
    unsigned short* Xs = X + (size_t)slice * SLICE_ELEMS;
    int d0 = slice * 32 + lane * 4;
    float4 bb = *(const float4*)&bias[d0];
    float c0 = 0.f, c1 = 0.f, c2 = 0.f, c3 = 0.f;
    unsigned* ps = pbuf + g * 68;
    int fg = chunk * 32 + g;         // flat group id in [0, 16384)
    for (int idx = fg; idx < N_NODES; idx += TOTAL_GROUPS) {
        int n = perm[idx];
        int beg = rowstart[idx], end = rowstart[idx + 1];   // length multiple of 16
        float a0 = 0.f, a1 = 0.f, a2 = 0.f, a3 = 0.f;
        uint4 u = *(const uint4*)(csr4 + beg + (lane << 2));
        int r = 0;
        for (int e = beg; e < end; e += 32, ++r) {
            int en = (e + 32 < end) ? e + 32 : e;
            uint4 un = *(const uint4*)(csr4 + en + (lane << 2));
            unsigned* pb = ps + (r & 1) * 32;
            *(uint4*)(pb + (lane << 2)) = u;
#pragma unroll
            for (int s = 0; s < 2; ++s) {
                if (e + (s << 4) >= end) break;
                unsigned pp[16];
#pragma unroll
                for (int i = 0; i < 16; ++i) pp[i] = pb[(s << 4) + i];
                uint2 q[16];
#pragma unroll
                for (int i = 0; i < 16; ++i)
                    q[i] = *(const uint2*)(Hb + ((pp[i] >> 16) << 6));
#pragma unroll
                for (int i = 0; i < 16; ++i) {
                    float nm = __uint_as_float(pp[i] << 16);
                    a0 = fmaf(nm, __uint_as_float(q[i].x << 16), a0);
                    a1 = fmaf(nm, __uint_as_float(q[i].x & 0xFFFF0000u), a1);
                    a2 = fmaf(nm, __uint_as_float(q[i].y << 16), a2);
                    a3 = fmaf(nm, __uint_as_float(q[i].y & 0xFFFF0000u), a3);
                }
            }
            u = un;
        }
        float o0 = fmaxf(a0 + bb.x, 0.f);
        float o1 = fmaxf(a1 + bb.y, 0.f);
        float o2 = fmaxf(a2 + bb.z, 0.f);
        float o3 = fmaxf(a3 + bb.w, 0.f);
        if (write_out) {
            ushort4_t o; o.x = f2b(o0); o.y = f2b(o1); o.z = f2b(o2); o.w = f2b(o3);
            *(ushort4_t*)(Xs + (size_t)n * 32 + (lane << 2)) = o;
        }
        c0 += o0; c1 += o1; c2 += o2; c3 += o3;
    }
    if (gsum) {
        __shared__ float4 smr[256];
        int tid = threadIdx.x;
        smr[tid] = make_float4(c0, c1, c2, c3);
        __syncthreads();
#pragma unroll
        for (int off = 128; off >= 8; off >>= 1) {
            if (tid < off) {
                float4 a = smr[tid], b = smr[tid + off];
                smr[tid] = make_float4(a.x + b.x, a.y + b.y, a.z + b.z, a.w + b.w);
            }
            __syncthreads();
        }
        if (tid < 8) {   // tid == lane, d0 matches
            float4 v = smr[tid];
            atomicAdd(&gsum[d0], v.x);
            atomicAdd(&gsum[d0 + 1], v.y);
            atomicAdd(&gsum[d0 + 2], v.z);
            atomicAdd(&gsum[d0 + 3], v.w);
        }
    }
}

// ---------------- FC head (single block, fp32) ----------------

__global__ __launch_bounds__(256) void k_fc(const float* __restrict__ gsum,
                                            const float* __restrict__ fcW1,
                                            const float* __restrict__ fcb1,
                                            const float* __restrict__ fcW2,
                                            const float* __restrict__ fcb2,
                                            const float* __restrict__ fcW3,
                                            const float* __restrict__ fcb3,
                                            float* __restrict__ out) {
    __shared__ float g[DIM];
    __shared__ float h[DIM];
    int t = threadIdx.x;
    g[t] = fmaxf(gsum[t] * (1.0f / (float)N_NODES), 0.f);
    __syncthreads();
    float acc = fcb1[t];
    for (int k = 0; k < DIM; ++k) acc = fmaf(g[k], fcW1[k * DIM + t], acc);
    h[t] = fmaxf(acc, 0.f);
    __syncthreads();
    acc = fcb2[t];
    for (int k = 0; k < DIM; ++k) acc = fmaf(h[k], fcW2[k * DIM + t], acc);
    __syncthreads();
    g[t] = fmaxf(acc, 0.f);
    __syncthreads();
    if (t < ACT) {
        float o = fcb3[t];
        for (int k = 0; k < DIM; ++k) o = fmaf(g[k], fcW3[k * ACT + t], o);
        out[t] = o;
    }
}

// ---------------- launch ----------------

extern "C" void kernel_launch(void* const* d_in, const int* in_sizes, int n_in,
                              void* d_out, int out_size, void* d_ws, size_t ws_size,
                              hipStream_t stream) {
    const float* x    = (const float*)d_in[0];
    const int*   ei   = (const int*)d_in[1];
    const float* W1   = (const float*)d_in[2];
    const float* b1   = (const float*)d_in[3];
    const float* W2   = (const float*)d_in[4];
    const float* b2   = (const float*)d_in[5];
    const float* fcW1 = (const float*)d_in[6];
    const float* fcb1 = (const float*)d_in[7];
    const float* fcW2 = (const float*)d_in[8];
    const float* fcb2 = (const float*)d_in[9];
    const float* fcW3 = (const float*)d_in[10];
    const float* fcb3 = (const float*)d_in[11];
    float* out = (float*)d_out;

    char* w = (char*)d_ws;
    size_t o = 0;
#define CARVE(name, type, count) \
    type* name = (type*)(w + o); \
    o += (((size_t)(count) * sizeof(type)) + 255) & ~(size_t)255;
    CARVE(degi, int, N_NODES)
    CARVE(rowstart, int, N_NODES + 1)
    CARVE(fillpos, int, N_NODES)
    CARVE(dinv, float, N_NODES)
    CARVE(lexc, int, N_NODES)
    CARVE(btot, int, SCAN_NB)
    CARVE(bbase, int, SCAN_NB)
    CARVE(blockbin, int, NBB)
    CARVE(blockbase, int, NBB)
    CARVE(perm, int, N_NODES)
    CARVE(lrank, unsigned char, N_NODES)
    CARVE(csr4, unsigned, CSR_MAX)
    CARVE(gsum, float, DIM)
    CARVE(W1t, unsigned short, DIM * DIM)
    CARVE(W2t, unsigned short, DIM * DIM)
    CARVE(Hbuf, unsigned short, (size_t)N_NODES * DIM)  // bf16 sliced
    CARVE(Xbuf, unsigned short, (size_t)N_NODES * DIM)  // bf16 sliced
#undef CARVE

    hipMemsetAsync(gsum, 0, DIM * sizeof(float), stream);
    hipMemsetAsync(degi, 0, N_NODES * sizeof(int), stream);
    hipMemsetAsync(csr4, 0, (size_t)CSR_MAX * sizeof(unsigned), stream);  // padding = (src0, +0.0)

    // weight prep
    k_cvt_wt2<<<512, 256, 0, stream>>>(W1, W2, W1t, W2t);

    // degree -> sort -> physically-sorted padded CSR (4B packed pairs)
    k_deg_count<<<(N_EDGES + 255) / 256, 256, 0, stream>>>(ei, degi);
    k_hist_rank<<<SCAN_NB, 256, 0, stream>>>(degi, blockbin, lrank);
    k_scan_bins<<<1, 256, 0, stream>>>(blockbin, blockbase);
    k_perm_apply<<<SCAN_NB, 256, 0, stream>>>(degi, blockbase, lrank, perm);
    k_scan_local<<<SCAN_NB, SCAN_B, 0, stream>>>(degi, perm, lexc, btot);
    k_scan_tops<<<1, SCAN_B, 0, stream>>>(btot, bbase, rowstart);
    k_scan_apply<<<SCAN_NB, SCAN_B, 0, stream>>>(degi, perm, lexc, bbase, rowstart,
                                                 fillpos, dinv, csr4);
    k_fill_edge<<<(N_EDGES + 255) / 256, 256, 0, stream>>>(ei, dinv, fillpos, csr4);

    // layer 1 (GEMM converts x fp32->bf16 in-staging)
    int gemm_grid = (N_NODES + 127) / 128;   // 391
    k_gemm_mfma<1><<<gemm_grid, 512, 0, stream>>>(x, W1t, Hbuf, N_NODES);
    k_agg_sliced<<<8 * AGG_CHUNKS, 256, 0, stream>>>(Hbuf, rowstart, csr4, perm, b1,
                                                     Xbuf, (float*)nullptr, 1);
    // layer 2 (agg fuses mean-pool column sum, no X write)
    k_gemm_mfma<0><<<gemm_grid, 512, 0, stream>>>(Xbuf, W2t, Hbuf, N_NODES);
    k_agg_sliced<<<8 * AGG_CHUNKS, 256, 0, stream>>>(Hbuf, rowstart, csr4, perm, b2,
                                                     Xbuf, gsum, 0);

    // head
    k_fc<<<1, 256, 0, stream>>>(gsum, fcW1, fcb1, fcW2, fcb2, fcW3, fcb3, out);
}

// Round 15
// 266.569 us; speedup vs baseline: 3.8479x; 1.0556x over previous
//
#include <hip/hip_runtime.h>

#define N_NODES 50000
#define N_EDGES 800000
#define DIM 256
#define ACT 64
#define SCAN_B 256
#define SCAN_NB ((N_NODES + SCAN_B - 1) / SCAN_B)   // 196
#define SLICE_ELEMS ((size_t)N_NODES * 32)          // elems per 32-dim slice
#define AGG_CHUNKS 512
#define TOTAL_GROUPS (AGG_CHUNKS * 32)              // 16384 groups per slice
#define CSR_MAX (N_EDGES + 16 * N_NODES + 64)       // padded-to-16 CSR + overread slack
#define NBINS 16
#define NBB (NBINS * SCAN_NB)                       // 3136 (bin,block) cells

typedef __attribute__((ext_vector_type(8))) short short8_t;
typedef __attribute__((ext_vector_type(4))) float f32x4;
typedef __attribute__((ext_vector_type(4))) unsigned short ushort4_t;

__device__ __forceinline__ unsigned short f2b(float x) {   // f32 -> bf16 RNE
    unsigned u = __float_as_uint(x);
    unsigned r = u + 0x7FFFu + ((u >> 16) & 1u);
    return (unsigned short)(r >> 16);
}

// DESCENDING bin: largest rows first -> final partial iteration gets smallest rows
__device__ __forceinline__ int deg_bin_desc(int deg) {
    int rounds = ((deg + 16) & ~15) >> 4;   // padded-16 slots / 16
    if (rounds > NBINS - 1) rounds = NBINS - 1;
    return (NBINS - 1) - rounds;
}

// ---------------- weight transpose + convert ----------------

__global__ __launch_bounds__(256) void k_cvt_wt2(const float* __restrict__ W1,
                                                 const float* __restrict__ W2,
                                                 unsigned short* __restrict__ W1t,
                                                 unsigned short* __restrict__ W2t) {
    int b = blockIdx.x;
    const float* W = (b < 256) ? W1 : W2;
    unsigned short* Wt = (b < 256) ? W1t : W2t;
    int i = (b & 255) * 256 + threadIdx.x;
    int k = i >> 8, n = i & 255;
    Wt[n * DIM + k] = f2b(W[k * DIM + n]);
}

// ---------------- degree (degi pre-zeroed; self-loop accounted as +1 in scan) ----------------

__global__ void k_deg_count(const int* __restrict__ ei, int* degi) {
    int e = blockIdx.x * blockDim.x + threadIdx.x;
    if (e < N_EDGES) atomicAdd(&degi[ei[N_EDGES + e]], 1);  // dst row
}

// ---------------- contention-free counting sort by round count (descending) ----------------

__global__ __launch_bounds__(256) void k_hist_rank(const int* __restrict__ degi,
                                                   int* blockbin,
                                                   unsigned char* lrank) {
    __shared__ int lh[NBINS];
    int t = threadIdx.x;
    if (t < NBINS) lh[t] = 0;
    __syncthreads();
    int i = blockIdx.x * 256 + t;
    if (i < N_NODES) {
        int bin = deg_bin_desc(degi[i]);
        lrank[i] = (unsigned char)atomicAdd(&lh[bin], 1);   // LDS atomic: block-local
    }
    __syncthreads();
    if (t < NBINS) blockbin[t * SCAN_NB + blockIdx.x] = lh[t];   // bin-major
}

__global__ __launch_bounds__(256) void k_scan_bins(const int* __restrict__ blockbin,
                                                   int* blockbase) {
    __shared__ int sm[256];
    int t = threadIdx.x;
    const int CH = (NBB + 255) / 256;   // 13
    int s0 = t * CH;
    int s1 = s0 + CH; if (s1 > NBB) s1 = NBB;
    int s = 0;
    for (int i = s0; i < s1; ++i) s += blockbin[i];
    sm[t] = s;
    __syncthreads();
#pragma unroll
    for (int off = 1; off < 256; off <<= 1) {
        int u = (t >= off) ? sm[t - off] : 0;
        __syncthreads();
        sm[t] += u;
        __syncthreads();
    }
    int base = sm[t] - s;
    for (int i = s0; i < s1; ++i) { int v = blockbin[i]; blockbase[i] = base; base += v; }
}

__global__ __launch_bounds__(256) void k_perm_apply(const int* __restrict__ degi,
                                                    const int* __restrict__ blockbase,
                                                    const unsigned char* __restrict__ lrank,
                                                    int* perm) {
    int i = blockIdx.x * 256 + threadIdx.x;
    if (i >= N_NODES) return;
    int bin = deg_bin_desc(degi[i]);
    perm[blockbase[bin * SCAN_NB + blockIdx.x] + lrank[i]] = i;
}

// ---------------- scan over PADDED row lengths in SORTED order ----------------
// padded_len = roundup16(deg+1); rowstart indexed by SORTED position ->
// csr4 is physically laid out in degree-sorted order (streaming locality in agg).

__global__ __launch_bounds__(SCAN_B) void k_scan_local(const int* __restrict__ degi,
                                                       const int* __restrict__ perm,
                                                       int* lexc, int* btot) {
    __shared__ int sm[SCAN_B];
    int t = threadIdx.x;
    int i = blockIdx.x * SCAN_B + t;
    int v = (i < N_NODES) ? ((degi[perm[i]] + 16) & ~15) : 0;   // roundup16(deg+1)
    sm[t] = v;
    __syncthreads();
#pragma unroll
    for (int off = 1; off < SCAN_B; off <<= 1) {
        int u = (t >= off) ? sm[t - off] : 0;
        __syncthreads();
        sm[t] += u;
        __syncthreads();
    }
    if (i < N_NODES) lexc[i] = sm[t] - v;
    if (t == SCAN_B - 1) btot[blockIdx.x] = sm[t];
}

__global__ __launch_bounds__(SCAN_B) void k_scan_tops(const int* __restrict__ btot,
                                                      int* bbase, int* rowstart) {
    __shared__ int sm[SCAN_B];
    int t = threadIdx.x;
    int v = (t < SCAN_NB) ? btot[t] : 0;
    sm[t] = v;
    __syncthreads();
#pragma unroll
    for (int off = 1; off < SCAN_B; off <<= 1) {
        int u = (t >= off) ? sm[t - off] : 0;
        __syncthreads();
        sm[t] += u;
        __syncthreads();
    }
    if (t < SCAN_NB) bbase[t] = sm[t] - v;
    if (t == SCAN_NB - 1) rowstart[N_NODES] = sm[t];
}

// csr4 entry: (src << 16) | bf16(norm). Sorted position i -> node perm[i].
__global__ __launch_bounds__(SCAN_B) void k_scan_apply(const int* __restrict__ degi,
                                                       const int* __restrict__ perm,
                                                       const int* __restrict__ lexc,
                                                       const int* __restrict__ bbase,
                                                       int* rowstart, int* fillpos,
                                                       float* dinv, unsigned* csr4) {
    int i = blockIdx.x * SCAN_B + threadIdx.x;
    if (i >= N_NODES) return;
    int rs = bbase[blockIdx.x] + lexc[i];
    rowstart[i] = rs;                    // sorted-order rowstart
    int n = perm[i];
    int d = degi[n] + 1;
    float di = rsqrtf((float)d);
    dinv[n] = di;
    csr4[rs] = ((unsigned)n << 16) | f2b(di * di);   // self-loop first in row
    fillpos[n] = rs + 1;                 // fill positions indexed by NODE
}

__global__ void k_fill_edge(const int* __restrict__ ei,
                            const float* __restrict__ dinv, int* fillpos,
                            unsigned* csr4) {
    int e = blockIdx.x * blockDim.x + threadIdx.x;
    if (e < N_EDGES) {
        int s = ei[e];
        int d = ei[N_EDGES + e];
        int p = atomicAdd(&fillpos[d], 1);
        csr4[p] = ((unsigned)s << 16) | f2b(dinv[s] * dinv[d]);
    }
}

// ---------------- bf16 MFMA GEMM: H = A @ Wt^T  (H SLICED; A fp32 row-major or sliced bf16) --

template <int AFP32>
__global__ __launch_bounds__(512) void k_gemm_mfma(const void* __restrict__ Ap,
                                                   const unsigned short* __restrict__ Wt,
                                                   unsigned short* __restrict__ H,
                                                   int M) {
    __shared__ char lds[49152];          // As 128x64 bf16 (16KB) + Bs 256x64 bf16 (32KB)
    char* AsB = lds;
    char* BsB = lds + 16384;

    int tid = threadIdx.x;
    int w = tid >> 6;
    int l = tid & 63;
    int wr = w >> 2, wc = w & 3;
    int r0 = blockIdx.x * 128;

    f32x4 acc[4][4];
#pragma unroll
    for (int i = 0; i < 4; ++i)
#pragma unroll
        for (int j = 0; j < 4; ++j) acc[i][j] = (f32x4)(0.f);

    for (int kt = 0; kt < 4; ++kt) {
        int k0 = kt * 64;
#pragma unroll
        for (int i = 0; i < 2; ++i) {
            int c = tid + i * 512;
            int row = c >> 3, kc = c & 7;
            int gg = r0 + row; if (gg >= M) gg = M - 1;
            short8_t v;
            if (AFP32) {
                const float* A = (const float*)Ap;
                const float4* src = (const float4*)(A + (size_t)gg * DIM + k0 + kc * 8);
                float4 f0 = src[0], f1 = src[1];
                v[0] = (short)f2b(f0.x); v[1] = (short)f2b(f0.y);
                v[2] = (short)f2b(f0.z); v[3] = (short)f2b(f0.w);
                v[4] = (short)f2b(f1.x); v[5] = (short)f2b(f1.y);
                v[6] = (short)f2b(f1.z); v[7] = (short)f2b(f1.w);
            } else {
                const unsigned short* A = (const unsigned short*)Ap;
                int k = k0 + kc * 8;
                int slice = k >> 5, within = k & 31;
                v = *(const short8_t*)(A + (size_t)slice * SLICE_ELEMS + (size_t)gg * 32 + within);
            }
            int off = (row * 128 + kc * 16) ^ ((row & 7) << 4);
            *(short8_t*)(AsB + off) = v;
        }
#pragma unroll
        for (int i = 0; i < 4; ++i) {
            int c = tid + i * 512;
            int n = c >> 3, kc = c & 7;
            short8_t v = *(const short8_t*)(Wt + n * DIM + k0 + kc * 8);
            int off = (n * 128 + kc * 16) ^ ((n & 7) << 4);
            *(short8_t*)(BsB + off) = v;
        }
        __syncthreads();

#pragma unroll
        for (int kf = 0; kf < 2; ++kf) {
            int kb = kf * 64 + (l >> 4) * 16;
            short8_t a[4], b[4];
#pragma unroll
            for (int fm = 0; fm < 4; ++fm) {
                int ra = wr * 64 + fm * 16 + (l & 15);
                a[fm] = *(const short8_t*)(AsB + ((ra * 128 + kb) ^ ((ra & 7) << 4)));
            }
#pragma unroll
            for (int fn = 0; fn < 4; ++fn) {
                int nb = wc * 64 + fn * 16 + (l & 15);
                b[fn] = *(const short8_t*)(BsB + ((nb * 128 + kb) ^ ((nb & 7) << 4)));
            }
#pragma unroll
            for (int fm = 0; fm < 4; ++fm)
#pragma unroll
                for (int fn = 0; fn < 4; ++fn)
                    acc[fm][fn] = __builtin_amdgcn_mfma_f32_16x16x32_bf16(
                        a[fm], b[fn], acc[fm][fn], 0, 0, 0);
        }
        __syncthreads();
    }

#pragma unroll
    for (int fm = 0; fm < 4; ++fm) {
#pragma unroll
        for (int i = 0; i < 4; ++i) {
            int row = r0 + wr * 64 + fm * 16 + ((l >> 4) << 2) + i;
            if (row >= M) continue;
#pragma unroll
            for (int fn = 0; fn < 4; ++fn) {
                int col = wc * 64 + fn * 16 + (l & 15);
                int slice = col >> 5;
                H[(size_t)slice * SLICE_ELEMS + (size_t)row * 32 + (col & 31)] = f2b(acc[fm][fn][i]);
            }
        }
    }
}

// ---------------- sliced aggregation v7: sorted CSR + 16-deep register-batched gathers ----

__global__ __launch_bounds__(256) void k_agg_sliced(const unsigned short* __restrict__ H,
                                                    const int* __restrict__ rowstart,
                                                    const unsigned* __restrict__ csr4,
                                                    const int* __restrict__ perm,
                                                    const float* __restrict__ bias,
                                                    unsigned short* __restrict__ X,
                                                    float* __restrict__ gsum,
                                                    int write_out) {
    __shared__ unsigned pbuf[32 * 68];      // 32 groups x (2 x 32 + 4 pad)
    int slice = blockIdx.x & 7;
    int chunk = blockIdx.x >> 3;
    int g = threadIdx.x >> 3;        // 32 groups of 8 lanes
    int lane = threadIdx.x & 7;
    const char* Hb = (const char*)(H + (size_t)slice * SLICE_ELEMS) + (lane << 3);
    unsigned short* Xs = X + (size_t)slice * SLICE_ELEMS;
    int d0 = slice * 32 + lane * 4;
    float4 bb = *(const float4*)&bias[d0];
    float c0 = 0.f, c1 = 0.f, c2 = 0.f, c3 = 0.f;
    unsigned* ps = pbuf + g * 68;
    int fg = chunk * 32 + g;         // flat group id in [0, 16384)
    for (int idx = fg; idx < N_NODES; idx += TOTAL_GROUPS) {
        int n = perm[idx];
        int beg = rowstart[idx], end = rowstart[idx + 1];   // length multiple of 16
        float a0 = 0.f, a1 = 0.f, a2 = 0.f, a3 = 0.f;
        uint4 u = *(const uint4*)(csr4 + beg + (lane << 2));
        int r = 0;
        for (int e = beg; e < end; e += 32, ++r) {
            int en = (e + 32 < end) ? e + 32 : e;
            uint4 un = *(const uint4*)(csr4 + en + (lane << 2));
            unsigned* pb = ps + (r & 1) * 32;
            *(uint4*)(pb + (lane << 2)) = u;
#pragma unroll
            for (int s = 0; s < 2; ++s) {
                if (e + (s << 4) >= end) break;
                unsigned pp[16];
#pragma unroll
                for (int i = 0; i < 16; ++i) pp[i] = pb[(s << 4) + i];
                uint2 q[16];
#pragma unroll
                for (int i = 0; i < 16; ++i)
                    q[i] = *(const uint2*)(Hb + ((pp[i] >> 16) << 6));
#pragma unroll
                for (int i = 0; i < 16; ++i) {
                    float nm = __uint_as_float(pp[i] << 16);
                    a0 = fmaf(nm, __uint_as_float(q[i].x << 16), a0);
                    a1 = fmaf(nm, __uint_as_float(q[i].x & 0xFFFF0000u), a1);
                    a2 = fmaf(nm, __uint_as_float(q[i].y << 16), a2);
                    a3 = fmaf(nm, __uint_as_float(q[i].y & 0xFFFF0000u), a3);
                }
            }
            u = un;
        }
        float o0 = fmaxf(a0 + bb.x, 0.f);
        float o1 = fmaxf(a1 + bb.y, 0.f);
        float o2 = fmaxf(a2 + bb.z, 0.f);
        float o3 = fmaxf(a3 + bb.w, 0.f);
        if (write_out) {
            ushort4_t o; o.x = f2b(o0); o.y = f2b(o1); o.z = f2b(o2); o.w = f2b(o3);
            *(ushort4_t*)(Xs + (size_t)n * 32 + (lane << 2)) = o;
        }
        c0 += o0; c1 += o1; c2 += o2; c3 += o3;
    }
    if (gsum) {
        __shared__ float4 smr[256];
        int tid = threadIdx.x;
        smr[tid] = make_float4(c0, c1, c2, c3);
        __syncthreads();
#pragma unroll
        for (int off = 128; off >= 8; off >>= 1) {
            if (tid < off) {
                float4 a = smr[tid], b = smr[tid + off];
                smr[tid] = make_float4(a.x + b.x, a.y + b.y, a.z + b.z, a.w + b.w);
            }
            __syncthreads();
        }
        if (tid < 8) {   // tid == lane, d0 matches
            float4 v = smr[tid];
            atomicAdd(&gsum[d0], v.x);
            atomicAdd(&gsum[d0 + 1], v.y);
            atomicAdd(&gsum[d0 + 2], v.z);
            atomicAdd(&gsum[d0 + 3], v.w);
        }
    }
}

// ---------------- FC head: 3 parallel kernels (16 outputs/block, 16 k-chunk partials) ------

template <int STRIDE, int RELU_IN, int RELU_OUT>
__global__ __launch_bounds__(256) void k_fcx(const float* __restrict__ gin,
                                             const float* __restrict__ W,
                                             const float* __restrict__ bias,
                                             float* __restrict__ gout,
                                             float scale) {
    __shared__ float red[16][17];
    int t = threadIdx.x;
    int lo = t & 15;                 // output within block
    int o = blockIdx.x * 16 + lo;
    int kc = t >> 4;                 // k-chunk of 16
    float acc = 0.f;
#pragma unroll
    for (int i = 0; i < 16; ++i) {
        int k = kc * 16 + i;
        float gv = gin[k] * scale;
        if (RELU_IN) gv = fmaxf(gv, 0.f);
        acc = fmaf(gv, W[k * STRIDE + o], acc);
    }
    red[kc][lo] = acc;
    __syncthreads();
    if (t < 16) {
        float s = bias[blockIdx.x * 16 + t];
#pragma unroll
        for (int j = 0; j < 16; ++j) s += red[j][t];
        if (RELU_OUT) s = fmaxf(s, 0.f);
        gout[blockIdx.x * 16 + t] = s;
    }
}

// ---------------- launch ----------------

extern "C" void kernel_launch(void* const* d_in, const int* in_sizes, int n_in,
                              void* d_out, int out_size, void* d_ws, size_t ws_size,
                              hipStream_t stream) {
    const float* x    = (const float*)d_in[0];
    const int*   ei   = (const int*)d_in[1];
    const float* W1   = (const float*)d_in[2];
    const float* b1   = (const float*)d_in[3];
    const float* W2   = (const float*)d_in[4];
    const float* b2   = (const float*)d_in[5];
    const float* fcW1 = (const float*)d_in[6];
    const float* fcb1 = (const float*)d_in[7];
    const float* fcW2 = (const float*)d_in[8];
    const float* fcb2 = (const float*)d_in[9];
    const float* fcW3 = (const float*)d_in[10];
    const float* fcb3 = (const float*)d_in[11];
    float* out = (float*)d_out;

    char* w = (char*)d_ws;
    size_t o = 0;
#define CARVE(name, type, count) \
    type* name = (type*)(w + o); \
    o += (((size_t)(count) * sizeof(type)) + 255) & ~(size_t)255;
    CARVE(degi, int, N_NODES)        // degi + gsum adjacent: single memset
    CARVE(gsum, float, DIM)
    CARVE(rowstart, int, N_NODES + 1)
    CARVE(fillpos, int, N_NODES)
    CARVE(dinv, float, N_NODES)
    CARVE(lexc, int, N_NODES)
    CARVE(btot, int, SCAN_NB)
    CARVE(bbase, int, SCAN_NB)
    CARVE(blockbin, int, NBB)
    CARVE(blockbase, int, NBB)
    CARVE(perm, int, N_NODES)
    CARVE(lrank, unsigned char, N_NODES)
    CARVE(csr4, unsigned, CSR_MAX)
    CARVE(g1, float, DIM)
    CARVE(g2, float, DIM)
    CARVE(W1t, unsigned short, DIM * DIM)
    CARVE(W2t, unsigned short, DIM * DIM)
    CARVE(Hbuf, unsigned short, (size_t)N_NODES * DIM)  // bf16 sliced
    CARVE(Xbuf, unsigned short, (size_t)N_NODES * DIM)  // bf16 sliced
#undef CARVE

    // one memset covers degi (first carve) through gsum (adjacent)
    hipMemsetAsync(degi, 0, (size_t)((char*)rowstart - (char*)degi), stream);
    hipMemsetAsync(csr4, 0, (size_t)CSR_MAX * sizeof(unsigned), stream);  // padding = (src0, +0.0)

    // weight prep
    k_cvt_wt2<<<512, 256, 0, stream>>>(W1, W2, W1t, W2t);

    // degree -> descending sort -> physically-sorted padded CSR (4B packed pairs)
    k_deg_count<<<(N_EDGES + 255) / 256, 256, 0, stream>>>(ei, degi);
    k_hist_rank<<<SCAN_NB, 256, 0, stream>>>(degi, blockbin, lrank);
    k_scan_bins<<<1, 256, 0, stream>>>(blockbin, blockbase);
    k_perm_apply<<<SCAN_NB, 256, 0, stream>>>(degi, blockbase, lrank, perm);
    k_scan_local<<<SCAN_NB, SCAN_B, 0, stream>>>(degi, perm, lexc, btot);
    k_scan_tops<<<1, SCAN_B, 0, stream>>>(btot, bbase, rowstart);
    k_scan_apply<<<SCAN_NB, SCAN_B, 0, stream>>>(degi, perm, lexc, bbase, rowstart,
                                                 fillpos, dinv, csr4);
    k_fill_edge<<<(N_EDGES + 255) / 256, 256, 0, stream>>>(ei, dinv, fillpos, csr4);

    // layer 1 (GEMM converts x fp32->bf16 in-staging)
    int gemm_grid = (N_NODES + 127) / 128;   // 391
    k_gemm_mfma<1><<<gemm_grid, 512, 0, stream>>>(x, W1t, Hbuf, N_NODES);
    k_agg_sliced<<<8 * AGG_CHUNKS, 256, 0, stream>>>(Hbuf, rowstart, csr4, perm, b1,
                                                     Xbuf, (float*)nullptr, 1);
    // layer 2 (agg fuses mean-pool column sum, no X write)
    k_gemm_mfma<0><<<gemm_grid, 512, 0, stream>>>(Xbuf, W2t, Hbuf, N_NODES);
    k_agg_sliced<<<8 * AGG_CHUNKS, 256, 0, stream>>>(Hbuf, rowstart, csr4, perm, b2,
                                                     Xbuf, gsum, 0);

    // head: mean+relu fused into fc1 input; 16/16/4-block parallel FC layers
    k_fcx<DIM, 1, 1><<<16, 256, 0, stream>>>(gsum, fcW1, fcb1, g1, 1.0f / (float)N_NODES);
    k_fcx<DIM, 0, 1><<<16, 256, 0, stream>>>(g1, fcW2, fcb2, g2, 1.0f);
    k_fcx<ACT, 0, 0><<<4, 256, 0, stream>>>(g2, fcW3, fcb3, out, 1.0f);
}

// Round 16
// 255.196 us; speedup vs baseline: 4.0193x; 1.0446x over previous
//
#include <hip/hip_runtime.h>

#define N_NODES 50000
#define N_EDGES 800000
#define DIM 256
#define ACT 64
#define SCAN_B 256
#define SCAN_NB ((N_NODES + SCAN_B - 1) / SCAN_B)   // 196
#define SLICE_ELEMS ((size_t)N_NODES * 32)          // elems per 32-dim slice
#define AGG_CHUNKS 512
#define TOTAL_GROUPS (AGG_CHUNKS * 32)              // 16384 groups per slice
#define CSR_MAX (N_EDGES + 16 * N_NODES + 64)       // padded-to-16 CSR + overread slack
#define NBINS 16
#define NBB (NBINS * SCAN_NB)                       // 3136 (bin,block) cells

typedef __attribute__((ext_vector_type(8))) short short8_t;
typedef __attribute__((ext_vector_type(4))) float f32x4;
typedef __attribute__((ext_vector_type(4))) unsigned short ushort4_t;

__device__ __forceinline__ unsigned short f2b(float x) {   // f32 -> bf16 RNE
    unsigned u = __float_as_uint(x);
    unsigned r = u + 0x7FFFu + ((u >> 16) & 1u);
    return (unsigned short)(r >> 16);
}

// DESCENDING bin: largest rows first. rounds = ceil((deg+1)/16) in [1,15].
__device__ __forceinline__ int deg_bin_desc(int deg) {
    int rounds = ((deg + 16) & ~15) >> 4;
    if (rounds > NBINS - 1) rounds = NBINS - 1;
    return (NBINS - 1) - rounds;
}

// direct global->LDS 16B copy (lane's data lands at ldsbase + lane*16)
__device__ __forceinline__ void gload_lds16(const void* g, void* l) {
    __builtin_amdgcn_global_load_lds(
        (const __attribute__((address_space(1))) void*)g,
        (__attribute__((address_space(3))) void*)l, 16, 0, 0);
}

// ---------------- weight transpose + convert into PRE-SWIZZLED staging order -------------
// Staged layout: per kt (4 tiles of 64 k), 2048 16B chunks; chunk c holds
// Wt[n][k0+kc*8 .. +8] with n=c>>3, kc=(c&7)^(n&7)  (inverse of the LDS XOR swizzle),
// so a linear global_load_lds places it at the swizzled LDS offset the reader expects.

__global__ __launch_bounds__(256) void k_cvt_wt2(const float* __restrict__ W1,
                                                 const float* __restrict__ W2,
                                                 unsigned short* __restrict__ W1s,
                                                 unsigned short* __restrict__ W2s) {
    int b = blockIdx.x;                      // 64 blocks
    const float* W = (b < 32) ? W1 : W2;
    unsigned short* Ws = (b < 32) ? W1s : W2s;
    int c = (b & 31) * 256 + threadIdx.x;    // global chunk 0..8191
    int kt = c >> 11, cc = c & 2047;
    int n = cc >> 3;
    int kc = (cc & 7) ^ (n & 7);
    int kbase = kt * 64 + kc * 8;
    short8_t v;
#pragma unroll
    for (int j = 0; j < 8; ++j) v[j] = (short)f2b(W[(kbase + j) * DIM + n]);
    *(short8_t*)(Ws + (size_t)c * 8) = v;
}

// ---------------- degree (degi pre-zeroed; self-loop accounted as +1) ----------------

__global__ void k_deg_count(const int* __restrict__ ei, int* degi) {
    int e = blockIdx.x * blockDim.x + threadIdx.x;
    if (e < N_EDGES) atomicAdd(&degi[ei[N_EDGES + e]], 1);  // dst row
}

// ---------------- contention-free counting sort (descending round count) ----------------

__global__ __launch_bounds__(256) void k_hist_rank(const int* __restrict__ degi,
                                                   int* blockbin,
                                                   unsigned char* lrank) {
    __shared__ int lh[NBINS];
    int t = threadIdx.x;
    if (t < NBINS) lh[t] = 0;
    __syncthreads();
    int i = blockIdx.x * 256 + t;
    if (i < N_NODES) {
        int bin = deg_bin_desc(degi[i]);
        lrank[i] = (unsigned char)atomicAdd(&lh[bin], 1);   // LDS atomic: block-local
    }
    __syncthreads();
    if (t < NBINS) blockbin[t * SCAN_NB + blockIdx.x] = lh[t];   // bin-major
}

// scan 3136 (bin,block) cells + derive analytic bin bases:
// binfo[b] = bin_start (node space), binfo[NBINS+1+b] = csr_base (slot space).
__global__ __launch_bounds__(256) void k_scan_bins(const int* __restrict__ blockbin,
                                                   int* blockbase, int* binfo,
                                                   int* rowstart) {
    __shared__ int sm[256];
    int t = threadIdx.x;
    const int CH = (NBB + 255) / 256;   // 13
    int s0 = t * CH;
    int s1 = s0 + CH; if (s1 > NBB) s1 = NBB;
    int s = 0;
    for (int i = s0; i < s1; ++i) s += blockbin[i];
    sm[t] = s;
    __syncthreads();
#pragma unroll
    for (int off = 1; off < 256; off <<= 1) {
        int u = (t >= off) ? sm[t - off] : 0;
        __syncthreads();
        sm[t] += u;
        __syncthreads();
    }
    int base = sm[t] - s;
    for (int i = s0; i < s1; ++i) { int v = blockbin[i]; blockbase[i] = base; base += v; }
    __syncthreads();
    if (t == 0) {
        int cacc = 0;
#pragma unroll
        for (int b = 0; b < NBINS; ++b) {
            int bs = blockbase[b * SCAN_NB];               // nodes in bins < b
            int bend = (b == NBINS - 1) ? N_NODES : blockbase[(b + 1) * SCAN_NB];
            binfo[b] = bs;
            binfo[NBINS + 1 + b] = cacc;
            cacc += (bend - bs) * (16 * (NBINS - 1 - b));  // count * plen(b)
        }
        binfo[NBINS] = N_NODES;
        rowstart[N_NODES] = cacc;                          // total padded slots
    }
}

// merged scatter: perm, analytic rowstart, dinv, self-loop entry, fillpos — one pass
__global__ __launch_bounds__(256) void k_perm_scatter(const int* __restrict__ degi,
                                                      const int* __restrict__ blockbase,
                                                      const int* __restrict__ binfo,
                                                      const unsigned char* __restrict__ lrank,
                                                      int* perm, int* rowstart,
                                                      int* fillpos, float* dinv,
                                                      unsigned* csr4) {
    int i = blockIdx.x * 256 + threadIdx.x;
    if (i >= N_NODES) return;
    int deg = degi[i];
    int bin = deg_bin_desc(deg);
    int pos = blockbase[bin * SCAN_NB + blockIdx.x] + lrank[i];
    perm[pos] = i;
    int plen = 16 * (NBINS - 1 - bin);
    int rs = binfo[NBINS + 1 + bin] + (pos - binfo[bin]) * plen;
    rowstart[pos] = rs;
    int d = deg + 1;
    float di = rsqrtf((float)d);
    dinv[i] = di;
    csr4[rs] = ((unsigned)i << 16) | f2b(di * di);   // self-loop first in row
    fillpos[i] = rs + 1;
}

__global__ void k_fill_edge(const int* __restrict__ ei,
                            const float* __restrict__ dinv, int* fillpos,
                            unsigned* csr4) {
    int e = blockIdx.x * blockDim.x + threadIdx.x;
    if (e < N_EDGES) {
        int s = ei[e];
        int d = ei[N_EDGES + e];
        int p = atomicAdd(&fillpos[d], 1);
        csr4[p] = ((unsigned)s << 16) | f2b(dinv[s] * dinv[d]);
    }
}

// ---------------- bf16 MFMA GEMM: H = A @ Wt^T  (H SLICED) ----------------
// B staged via global_load_lds from pre-swizzled WtS (linear LDS dest = swizzled layout).
// AFP32=1: A = x fp32 row-major, VGPR-convert staging (layer 1).
// AFP32=0: A = X bf16 ROW-MAJOR, staged via global_load_lds w/ swizzle-inverted src (layer 2).

template <int AFP32>
__global__ __launch_bounds__(512) void k_gemm_mfma(const void* __restrict__ Ap,
                                                   const unsigned short* __restrict__ WtS,
                                                   unsigned short* __restrict__ H,
                                                   int M) {
    __shared__ char lds[49152];          // As 128x64 bf16 (16KB) + Bs 256x64 bf16 (32KB)
    char* AsB = lds;
    char* BsB = lds + 16384;

    int tid = threadIdx.x;
    int w = tid >> 6;
    int l = tid & 63;
    int wr = w >> 2, wc = w & 3;
    int r0 = blockIdx.x * 128;

    f32x4 acc[4][4];
#pragma unroll
    for (int i = 0; i < 4; ++i)
#pragma unroll
        for (int j = 0; j < 4; ++j) acc[i][j] = (f32x4)(0.f);

    for (int kt = 0; kt < 4; ++kt) {
        int k0 = kt * 64;
        if (AFP32) {
            // A: 1024 chunks, VGPR fp32->bf16 convert + swizzled ds_write
            const float* A = (const float*)Ap;
#pragma unroll
            for (int i = 0; i < 2; ++i) {
                int c = tid + i * 512;
                int row = c >> 3, kc = c & 7;
                int gg = r0 + row; if (gg >= M) gg = M - 1;
                const float4* src = (const float4*)(A + (size_t)gg * DIM + k0 + kc * 8);
                float4 f0 = src[0], f1 = src[1];
                short8_t v;
                v[0] = (short)f2b(f0.x); v[1] = (short)f2b(f0.y);
                v[2] = (short)f2b(f0.z); v[3] = (short)f2b(f0.w);
                v[4] = (short)f2b(f1.x); v[5] = (short)f2b(f1.y);
                v[6] = (short)f2b(f1.z); v[7] = (short)f2b(f1.w);
                int off = (row * 128 + kc * 16) ^ ((row & 7) << 4);
                *(short8_t*)(AsB + off) = v;
            }
        } else {
            // A: 16 segments of 64 chunks; direct global->LDS with inverted-swizzle src
            const char* Arm = (const char*)Ap;   // bf16 row-major [node][256]
#pragma unroll
            for (int i = 0; i < 2; ++i) {
                int s = w * 2 + i;
                int c = s * 64 + l;
                int row = c >> 3;
                int kc = (c & 7) ^ (row & 7);
                int gg = r0 + row; if (gg >= M) gg = M - 1;
                gload_lds16(Arm + (size_t)gg * 512 + k0 * 2 + kc * 16, AsB + s * 1024);
            }
        }
        // B: 32 segments of 64 chunks; WtS already pre-swizzled -> pure linear copy
        {
            const char* Bsrc = (const char*)WtS + (size_t)kt * 32768;
#pragma unroll
            for (int i = 0; i < 4; ++i) {
                int s = w * 4 + i;
                gload_lds16(Bsrc + s * 1024 + l * 16, BsB + s * 1024);
            }
        }
        __syncthreads();

#pragma unroll
        for (int kf = 0; kf < 2; ++kf) {
            int kb = kf * 64 + (l >> 4) * 16;
            short8_t a[4], b[4];
#pragma unroll
            for (int fm = 0; fm < 4; ++fm) {
                int ra = wr * 64 + fm * 16 + (l & 15);
                a[fm] = *(const short8_t*)(AsB + ((ra * 128 + kb) ^ ((ra & 7) << 4)));
            }
#pragma unroll
            for (int fn = 0; fn < 4; ++fn) {
                int nb = wc * 64 + fn * 16 + (l & 15);
                b[fn] = *(const short8_t*)(BsB + ((nb * 128 + kb) ^ ((nb & 7) << 4)));
            }
#pragma unroll
            for (int fm = 0; fm < 4; ++fm)
#pragma unroll
                for (int fn = 0; fn < 4; ++fn)
                    acc[fm][fn] = __builtin_amdgcn_mfma_f32_16x16x32_bf16(
                        a[fm], b[fn], acc[fm][fn], 0, 0, 0);
        }
        __syncthreads();
    }

    // C/D layout: col = l&15, row = (l>>4)*4 + i ; write SLICED
#pragma unroll
    for (int fm = 0; fm < 4; ++fm) {
#pragma unroll
        for (int i = 0; i < 4; ++i) {
            int row = r0 + wr * 64 + fm * 16 + ((l >> 4) << 2) + i;
            if (row >= M) continue;
#pragma unroll
            for (int fn = 0; fn < 4; ++fn) {
                int col = wc * 64 + fn * 16 + (l & 15);
                int slice = col >> 5;
                H[(size_t)slice * SLICE_ELEMS + (size_t)row * 32 + (col & 31)] = f2b(acc[fm][fn][i]);
            }
        }
    }
}

// ---------------- sliced aggregation v7: sorted CSR + 16-deep register-batched gathers ----
// X output is ROW-MAJOR bf16 [node][256] (feeds layer-2 GEMM's global_load_lds staging).

__global__ __launch_bounds__(256) void k_agg_sliced(const unsigned short* __restrict__ H,
                                                    const int* __restrict__ rowstart,
                                                    const unsigned* __restrict__ csr4,
                                                    const int* __restrict__ perm,
                                                    const float* __restrict__ bias,
                                                    unsigned short* __restrict__ X,
                                                    float* __restrict__ gsum,
                                                    int write_out) {
    __shared__ unsigned pbuf[32 * 68];      // 32 groups x (2 x 32 + 4 pad)
    int slice = blockIdx.x & 7;
    int chunk = blockIdx.x >> 3;
    int g = threadIdx.x >> 3;        // 32 groups of 8 lanes
    int lane = threadIdx.x & 7;
    const char* Hb = (const char*)(H + (size_t)slice * SLICE_ELEMS) + (lane << 3);
    int d0 = slice * 32 + lane * 4;
    float4 bb = *(const float4*)&bias[d0];
    float c0 = 0.f, c1 = 0.f, c2 = 0.f, c3 = 0.f;
    unsigned* ps = pbuf + g * 68;
    int fg = chunk * 32 + g;         // flat group id in [0, 16384)
    for (int idx = fg; idx < N_NODES; idx += TOTAL_GROUPS) {
        int n = perm[idx];
        int beg = rowstart[idx], end = rowstart[idx + 1];   // length multiple of 16
        float a0 = 0.f, a1 = 0.f, a2 = 0.f, a3 = 0.f;
        uint4 u = *(const uint4*)(csr4 + beg + (lane << 2));
        int r = 0;
        for (int e = beg; e < end; e += 32, ++r) {
            int en = (e + 32 < end) ? e + 32 : e;
            uint4 un = *(const uint4*)(csr4 + en + (lane << 2));
            unsigned* pb = ps + (r & 1) * 32;
            *(uint4*)(pb + (lane << 2)) = u;
#pragma unroll
            for (int s = 0; s < 2; ++s) {
                if (e + (s << 4) >= end) break;
                unsigned pp[16];
#pragma unroll
                for (int i = 0; i < 16; ++i) pp[i] = pb[(s << 4) + i];
                uint2 q[16];
#pragma unroll
                for (int i = 0; i < 16; ++i)
                    q[i] = *(const uint2*)(Hb + ((pp[i] >> 16) << 6));
#pragma unroll
                for (int i = 0; i < 16; ++i) {
                    float nm = __uint_as_float(pp[i] << 16);
                    a0 = fmaf(nm, __uint_as_float(q[i].x << 16), a0);
                    a1 = fmaf(nm, __uint_as_float(q[i].x & 0xFFFF0000u), a1);
                    a2 = fmaf(nm, __uint_as_float(q[i].y << 16), a2);
                    a3 = fmaf(nm, __uint_as_float(q[i].y & 0xFFFF0000u), a3);
                }
            }
            u = un;
        }
        float o0 = fmaxf(a0 + bb.x, 0.f);
        float o1 = fmaxf(a1 + bb.y, 0.f);
        float o2 = fmaxf(a2 + bb.z, 0.f);
        float o3 = fmaxf(a3 + bb.w, 0.f);
        if (write_out) {
            ushort4_t o; o.x = f2b(o0); o.y = f2b(o1); o.z = f2b(o2); o.w = f2b(o3);
            *(ushort4_t*)(X + (size_t)n * DIM + slice * 32 + (lane << 2)) = o;  // row-major
        }
        c0 += o0; c1 += o1; c2 += o2; c3 += o3;
    }
    if (gsum) {
        __shared__ float4 smr[256];
        int tid = threadIdx.x;
        smr[tid] = make_float4(c0, c1, c2, c3);
        __syncthreads();
#pragma unroll
        for (int off = 128; off >= 8; off >>= 1) {
            if (tid < off) {
                float4 a = smr[tid], b = smr[tid + off];
                smr[tid] = make_float4(a.x + b.x, a.y + b.y, a.z + b.z, a.w + b.w);
            }
            __syncthreads();
        }
        if (tid < 8) {   // tid == lane, d0 matches
            float4 v = smr[tid];
            atomicAdd(&gsum[d0], v.x);
            atomicAdd(&gsum[d0 + 1], v.y);
            atomicAdd(&gsum[d0 + 2], v.z);
            atomicAdd(&gsum[d0 + 3], v.w);
        }
    }
}

// ---------------- FC head: 3 parallel kernels (16 outputs/block, 16 k-chunk partials) ------

template <int STRIDE, int RELU_IN, int RELU_OUT>
__global__ __launch_bounds__(256) void k_fcx(const float* __restrict__ gin,
                                             const float* __restrict__ W,
                                             const float* __restrict__ bias,
                                             float* __restrict__ gout,
                                             float scale) {
    __shared__ float red[16][17];
    int t = threadIdx.x;
    int lo = t & 15;                 // output within block
    int o = blockIdx.x * 16 + lo;
    int kc = t >> 4;                 // k-chunk of 16
    float acc = 0.f;
#pragma unroll
    for (int i = 0; i < 16; ++i) {
        int k = kc * 16 + i;
        float gv = gin[k] * scale;
        if (RELU_IN) gv = fmaxf(gv, 0.f);
        acc = fmaf(gv, W[k * STRIDE + o], acc);
    }
    red[kc][lo] = acc;
    __syncthreads();
    if (t < 16) {
        float s = bias[blockIdx.x * 16 + t];
#pragma unroll
        for (int j = 0; j < 16; ++j) s += red[j][t];
        if (RELU_OUT) s = fmaxf(s, 0.f);
        gout[blockIdx.x * 16 + t] = s;
    }
}

// ---------------- launch ----------------

extern "C" void kernel_launch(void* const* d_in, const int* in_sizes, int n_in,
                              void* d_out, int out_size, void* d_ws, size_t ws_size,
                              hipStream_t stream) {
    const float* x    = (const float*)d_in[0];
    const int*   ei   = (const int*)d_in[1];
    const float* W1   = (const float*)d_in[2];
    const float* b1   = (const float*)d_in[3];
    const float* W2   = (const float*)d_in[4];
    const float* b2   = (const float*)d_in[5];
    const float* fcW1 = (const float*)d_in[6];
    const float* fcb1 = (const float*)d_in[7];
    const float* fcW2 = (const float*)d_in[8];
    const float* fcb2 = (const float*)d_in[9];
    const float* fcW3 = (const float*)d_in[10];
    const float* fcb3 = (const float*)d_in[11];
    float* out = (float*)d_out;

    char* w = (char*)d_ws;
    size_t o = 0;
#define CARVE(name, type, count) \
    type* name = (type*)(w + o); \
    o += (((size_t)(count) * sizeof(type)) + 255) & ~(size_t)255;
    CARVE(degi, int, N_NODES)        // degi + gsum adjacent: single memset
    CARVE(gsum, float, DIM)
    CARVE(rowstart, int, N_NODES + 1)
    CARVE(fillpos, int, N_NODES)
    CARVE(dinv, float, N_NODES)
    CARVE(blockbin, int, NBB)
    CARVE(blockbase, int, NBB)
    CARVE(binfo, int, 2 * NBINS + 2)
    CARVE(perm, int, N_NODES)
    CARVE(lrank, unsigned char, N_NODES)
    CARVE(csr4, unsigned, CSR_MAX)
    CARVE(g1, float, DIM)
    CARVE(g2, float, DIM)
    CARVE(W1s, unsigned short, DIM * DIM)               // pre-swizzled staging order
    CARVE(W2s, unsigned short, DIM * DIM)
    CARVE(Hbuf, unsigned short, (size_t)N_NODES * DIM)  // bf16 SLICED (gather layout)
    CARVE(Xbuf, unsigned short, (size_t)N_NODES * DIM)  // bf16 ROW-MAJOR (gemm-A layout)
#undef CARVE

    // one memset covers degi (first carve) through gsum (adjacent)
    hipMemsetAsync(degi, 0, (size_t)((char*)rowstart - (char*)degi), stream);
    hipMemsetAsync(csr4, 0, (size_t)CSR_MAX * sizeof(unsigned), stream);  // padding = (src0, +0.0)

    // weight prep (pre-swizzled staging order)
    k_cvt_wt2<<<64, 256, 0, stream>>>(W1, W2, W1s, W2s);

    // degree -> descending sort -> physically-sorted padded CSR (5-kernel chain)
    k_deg_count<<<(N_EDGES + 255) / 256, 256, 0, stream>>>(ei, degi);
    k_hist_rank<<<SCAN_NB, 256, 0, stream>>>(degi, blockbin, lrank);
    k_scan_bins<<<1, 256, 0, stream>>>(blockbin, blockbase, binfo, rowstart);
    k_perm_scatter<<<SCAN_NB, 256, 0, stream>>>(degi, blockbase, binfo, lrank,
                                                perm, rowstart, fillpos, dinv, csr4);
    k_fill_edge<<<(N_EDGES + 255) / 256, 256, 0, stream>>>(ei, dinv, fillpos, csr4);

    // layer 1 (GEMM converts x fp32->bf16 in-staging; B via global_load_lds)
    int gemm_grid = (N_NODES + 127) / 128;   // 391
    k_gemm_mfma<1><<<gemm_grid, 512, 0, stream>>>(x, W1s, Hbuf, N_NODES);
    k_agg_sliced<<<8 * AGG_CHUNKS, 256, 0, stream>>>(Hbuf, rowstart, csr4, perm, b1,
                                                     Xbuf, (float*)nullptr, 1);
    // layer 2 (A and B both via global_load_lds; agg fuses mean-pool, no X write)
    k_gemm_mfma<0><<<gemm_grid, 512, 0, stream>>>(Xbuf, W2s, Hbuf, N_NODES);
    k_agg_sliced<<<8 * AGG_CHUNKS, 256, 0, stream>>>(Hbuf, rowstart, csr4, perm, b2,
                                                     Xbuf, gsum, 0);

    // head: mean+relu fused into fc1 input; 16/16/4-block parallel FC layers
    k_fcx<DIM, 1, 1><<<16, 256, 0, stream>>>(gsum, fcW1, fcb1, g1, 1.0f / (float)N_NODES);
    k_fcx<DIM, 0, 1><<<16, 256, 0, stream>>>(g1, fcW2, fcb2, g2, 1.0f);
    k_fcx<ACT, 0, 0><<<4, 256, 0, stream>>>(g2, fcW3, fcb3, out, 1.0f);
}